// Round 1
// baseline (606.207 us; speedup 1.0000x reference)
//
#include <hip/hip_runtime.h>
#include <math.h>

// Problem constants
#define T_TOK 1024
#define DIM 512
#define INTER 256
#define SINTER 1024
#define NEXP 64
#define TOPK 6

typedef unsigned short u16;
typedef unsigned int u32;
typedef short bf16x8 __attribute__((ext_vector_type(8)));   // 8 bf16 (4 VGPRs)
typedef float f32x4  __attribute__((ext_vector_type(4)));   // MFMA 16x16 accumulator

#define XP 520   // LDS x-tile row pitch (u16) = DIM+8  -> rows stride 4 banks: 2-way max (free)
#define HP 264   // LDS h/v-tile row pitch (u16) = INTER+8

__device__ __forceinline__ float bflo(u32 u) { return __uint_as_float(u << 16); }
__device__ __forceinline__ float bfhi(u32 u) { return __uint_as_float(u & 0xffff0000u); }

__device__ __forceinline__ u16 f2bf(float f) {
    u32 u = __float_as_uint(f);
    return (u16)((u + 0x7fffu + ((u >> 16) & 1u)) >> 16);  // RNE
}

__device__ __forceinline__ f32x4 mfma16(bf16x8 a, bf16x8 b, f32x4 c) {
    return __builtin_amdgcn_mfma_f32_16x16x32_bf16(a, b, c, 0, 0, 0);
}

// load 8 consecutive elements (idx must be a multiple of 8) as floats
template<bool BF>
__device__ __forceinline__ void ld8(const void* p, size_t idx, float* f) {
    if (BF) {
        uint4 u = *(const uint4*)((const u16*)p + idx);
        f[0] = bflo(u.x); f[1] = bfhi(u.x);
        f[2] = bflo(u.y); f[3] = bfhi(u.y);
        f[4] = bflo(u.z); f[5] = bfhi(u.z);
        f[6] = bflo(u.w); f[7] = bfhi(u.w);
    } else {
        const float4* q = (const float4*)((const float*)p + idx);
        float4 a = q[0], b = q[1];
        f[0] = a.x; f[1] = a.y; f[2] = a.z; f[3] = a.w;
        f[4] = b.x; f[5] = b.y; f[6] = b.z; f[7] = b.w;
    }
}

// load 2 consecutive elements (idx even)
template<bool BF>
__device__ __forceinline__ void ld2(const void* p, size_t idx, float& a, float& b) {
    if (BF) { u32 w = *(const u32*)((const u16*)p + idx); a = bflo(w); b = bfhi(w); }
    else    { float2 v = *(const float2*)((const float*)p + idx); a = v.x; b = v.y; }
}

__device__ __forceinline__ void fma44(float& acc, const float* f, const float4& a, const float4& b) {
    acc = fmaf(f[0], a.x, acc); acc = fmaf(f[1], a.y, acc);
    acc = fmaf(f[2], a.z, acc); acc = fmaf(f[3], a.w, acc);
    acc = fmaf(f[4], b.x, acc); acc = fmaf(f[5], b.y, acc);
    acc = fmaf(f[6], b.z, acc); acc = fmaf(f[7], b.w, acc);
}

// ---------------- kernel P: dtype probe ----------------
__global__ void k_probe(const u32* __restrict__ xw, int* __restrict__ flag) {
    int cnt = 0;
    #pragma unroll
    for (int i = 0; i < 8; ++i) {
        u32 u = xw[threadIdx.x * 8 + i];
        u32 e = (u >> 7) & 0xffu;           // exponent of low-half-as-bf16
        cnt += (e >= 110 && e <= 140) ? 1 : 0;
    }
    #pragma unroll
    for (int off = 32; off; off >>= 1) cnt += __shfl_xor(cnt, off);
    if (threadIdx.x == 0) flag[0] = (cnt > 256) ? 1 : 0;
}

// ---------------- kernel 0: zero the expert counters ----------------
__global__ void k_init(int* counts) {
    counts[threadIdx.x] = 0;
}

// ---------------- kernel 1: router (unchanged; handles both dtypes) ----------------
template<bool BF>
__device__ __forceinline__ void router_body(const void* __restrict__ xg,
                                            const void* __restrict__ wg,
                                            int* __restrict__ counts,
                                            int* __restrict__ topki,
                                            float* __restrict__ topkw,
                                            float* xs, float* svals, int* sidx) {
    const int t = blockIdx.x;
    const int lane = threadIdx.x;

    ld8<BF>(xg, (size_t)t * DIM + lane * 8, &xs[lane * 8]);
    __syncthreads();

    float acc = 0.f;
    for (int k = 0; k < 64; ++k) {
        float f[8]; ld8<BF>(wg, (size_t)lane * DIM + k * 8, f);
        float4 xa = *(const float4*)&xs[k * 8];
        float4 xb = *(const float4*)&xs[k * 8 + 4];
        fma44(acc, f, xa, xb);
    }

    float my = acc;
    for (int s = 0; s < TOPK; ++s) {
        float v = my; int id = lane;
        #pragma unroll
        for (int off = 32; off; off >>= 1) {
            float ov = __shfl_xor(v, off);
            int   oi = __shfl_xor(id, off);
            if (ov > v || (ov == v && oi < id)) { v = ov; id = oi; }
        }
        if (lane == 0) { svals[s] = v; sidx[s] = id; }
        if (lane == id) my = -INFINITY;
    }
    __syncthreads();
    if (lane == 0) {
        float m = svals[0], sum = 0.f, w[TOPK];
        #pragma unroll
        for (int s = 0; s < TOPK; ++s) { w[s] = __expf(svals[s] - m); sum += w[s]; }
        float inv = 1.f / sum;
        #pragma unroll
        for (int s = 0; s < TOPK; ++s) {
            int e = sidx[s];
            topki[t * TOPK + s] = e;
            topkw[t * TOPK + s] = w[s] * inv;
            atomicAdd(&counts[e], 1);
        }
    }
}

__global__ __launch_bounds__(64) void k_router(const void* xg, const void* wg,
                                               const int* __restrict__ flag,
                                               int* counts, int* topki, float* topkw) {
    __shared__ __align__(16) float xs[DIM];
    __shared__ float svals[TOPK];
    __shared__ int sidx[TOPK];
    if (*flag) router_body<true >(xg, wg, counts, topki, topkw, xs, svals, sidx);
    else       router_body<false>(xg, wg, counts, topki, topkw, xs, svals, sidx);
}

// ---------------- kernel 2: prefix sum over 64 experts ----------------
__global__ void k_prefix(const int* __restrict__ counts, int* __restrict__ offsets,
                         int* __restrict__ cursors) {
    if (threadIdx.x == 0) {
        int acc = 0;
        for (int e = 0; e < NEXP; ++e) { offsets[e] = acc; cursors[e] = acc; acc += counts[e]; }
    }
}

// ---------------- kernel 3: scatter tokens into expert buckets ----------------
__global__ void k_scatter(const int* __restrict__ topki, const float* __restrict__ topkw,
                          int* __restrict__ cursors, int* __restrict__ tokl,
                          float* __restrict__ wgtl) {
    int t = blockIdx.x * 256 + threadIdx.x;
    #pragma unroll
    for (int s = 0; s < TOPK; ++s) {
        int e = topki[t * TOPK + s];
        float w = topkw[t * TOPK + s];
        int pos = atomicAdd(&cursors[e], 1);
        tokl[pos] = t;
        wgtl[pos] = w;
    }
}

// ---------------- kernel W: transpose w2 -> w2t[e][d][i] (bf16 path only) ----------------
// w2 is stored [e][inter][dim] = [K][N]; MFMA B-fragments need [N][K] contiguous-K.
__global__ __launch_bounds__(256) void k_w2t(const u16* __restrict__ w2,
                                             u16* __restrict__ w2t,
                                             const int* __restrict__ flag) {
    if (!*flag) return;
    __shared__ u16 lt[256][72];
    const int e  = blockIdx.x >> 3;
    const int dc = blockIdx.x & 7;           // 64-dim chunk
    const int tid = threadIdx.x;
    const u16* src = w2 + (size_t)e * INTER * DIM + dc * 64;
    #pragma unroll
    for (int p = 0; p < 8; ++p) {
        int idx = p * 256 + tid;
        int i = idx >> 3, c8 = idx & 7;
        *(uint4*)&lt[i][c8 * 8] = *(const uint4*)(src + (size_t)i * DIM + c8 * 8);
    }
    __syncthreads();
    const int dl = tid >> 2, q = tid & 3;    // out row d = dc*64+dl, quarter q of 256 i's
    u16* dst = w2t + (size_t)e * DIM * INTER + (size_t)(dc * 64 + dl) * INTER + q * 64;
    u32 buf[32];
    #pragma unroll
    for (int ii = 0; ii < 32; ++ii) {
        int i = q * 64 + ii * 2;
        buf[ii] = (u32)lt[i][dl] | ((u32)lt[i + 1][dl] << 16);
    }
    #pragma unroll
    for (int s = 0; s < 8; ++s)
        *(uint4*)(dst + s * 8) = *(uint4*)&buf[s * 4];
}

// ---------------- kernel SA: shared expert, V = silu(X Wsg^T) * (X Wsu^T) ----------------
__global__ __launch_bounds__(256) void k_shA(const u16* __restrict__ xg,
                                             const u16* __restrict__ wsg,
                                             const u16* __restrict__ wsu,
                                             u16* __restrict__ vout,
                                             const int* __restrict__ flag) {
    if (!*flag) return;
    __shared__ __align__(16) u16 xs[16 * XP];
    __shared__ __align__(16) u16 vs[16 * HP];
    const int tt = blockIdx.x >> 2;          // token tile (16 rows)
    const int sc = blockIdx.x & 3;           // sinter chunk of 256
    const int tid = threadIdx.x;
    const int w = tid >> 6, lane = tid & 63;
    const int lr = lane & 15, lg = lane >> 4;

    const u16* xb = xg + (size_t)(tt * 16) * DIM;
    for (int idx = tid; idx < 16 * 64; idx += 256) {
        int r = idx >> 6, c = idx & 63;
        *(uint4*)&xs[r * XP + c * 8] = *(const uint4*)(xb + (size_t)r * DIM + c * 8);
    }
    __syncthreads();

    const f32x4 z4 = {0.f, 0.f, 0.f, 0.f};
    f32x4 ag[4] = {z4, z4, z4, z4};
    f32x4 au[4] = {z4, z4, z4, z4};
    const int j0 = sc * 256 + w * 64;        // this wave's sinter base
    for (int ks = 0; ks < 16; ++ks) {
        const int k0 = ks * 32 + lg * 8;
        bf16x8 a = *(const bf16x8*)&xs[lr * XP + k0];
        #pragma unroll
        for (int nt = 0; nt < 4; ++nt) {
            const size_t row = (size_t)(j0 + nt * 16 + lr) * DIM + k0;
            ag[nt] = mfma16(a, *(const bf16x8*)(wsg + row), ag[nt]);
            au[nt] = mfma16(a, *(const bf16x8*)(wsu + row), au[nt]);
        }
    }
    #pragma unroll
    for (int nt = 0; nt < 4; ++nt) {
        #pragma unroll
        for (int r = 0; r < 4; ++r) {
            float g = ag[nt][r];
            float v = g / (1.f + __expf(-g)) * au[nt][r];
            vs[(lg * 4 + r) * HP + w * 64 + nt * 16 + lr] = f2bf(v);
        }
    }
    __syncthreads();
    #pragma unroll
    for (int p = 0; p < 2; ++p) {
        int idx = p * 256 + tid;
        int r = idx >> 5, c = idx & 31;
        *(uint4*)(vout + (size_t)(tt * 16 + r) * SINTER + sc * 256 + c * 8) =
            *(const uint4*)&vs[r * HP + c * 8];
    }
}

// ---------------- kernel SB: shared expert, accum = V @ Wsd^T ----------------
// No LDS, no barriers: A-fragments straight from V (L2-hot), B from wsd [DIM][SINTER]=[N][K].
__global__ __launch_bounds__(256) void k_shB(const u16* __restrict__ vin,
                                             const u16* __restrict__ wsd,
                                             float* __restrict__ accum,
                                             const int* __restrict__ flag) {
    if (!*flag) return;
    const int tt = blockIdx.x >> 3;          // token tile (16)
    const int dc = blockIdx.x & 7;           // 64-dim chunk
    const int w = threadIdx.x >> 6, lane = threadIdx.x & 63;
    const int lr = lane & 15, lg = lane >> 4;
    const int d0 = dc * 64 + w * 16;
    const u16* vrow = vin + (size_t)(tt * 16 + lr) * SINTER;
    const u16* wrow = wsd + (size_t)(d0 + lr) * SINTER;
    f32x4 acc = {0.f, 0.f, 0.f, 0.f};
    for (int ks = 0; ks < 32; ++ks) {
        const int k0 = ks * 32 + lg * 8;
        acc = mfma16(*(const bf16x8*)(vrow + k0), *(const bf16x8*)(wrow + k0), acc);
    }
    #pragma unroll
    for (int r = 0; r < 4; ++r)
        accum[(size_t)(tt * 16 + lg * 4 + r) * DIM + d0 + lr] = acc[r];
}

// ---------------- kernel 4 (fp32 fallback): shared expert ----------------
template<bool BF>
__device__ __forceinline__ void shared_body(const void* __restrict__ xg,
                                            const void* __restrict__ wsg,
                                            const void* __restrict__ wsu,
                                            const void* __restrict__ wsd,
                                            float* __restrict__ accum,
                                            float* xs /*8*DIM*/, float* vsf /*8*SINTER*/) {
    const int t0 = blockIdx.x * 8;
    const int tid = threadIdx.x;

    for (int idx = tid; idx < 8 * 64; idx += 256) {
        int r = idx >> 6, c = idx & 63;
        ld8<BF>(xg, (size_t)(t0 + r) * DIM + c * 8, &xs[r * DIM + c * 8]);
    }
    __syncthreads();

    for (int jc = 0; jc < 4; ++jc) {
        int j = jc * 256 + tid;
        float ag[8] = {0}, au[8] = {0};
        for (int k = 0; k < 64; ++k) {
            float fg[8], fu[8];
            ld8<BF>(wsg, (size_t)j * DIM + k * 8, fg);
            ld8<BF>(wsu, (size_t)j * DIM + k * 8, fu);
            #pragma unroll
            for (int r = 0; r < 8; ++r) {
                float4 xa = *(const float4*)&xs[r * DIM + k * 8];
                float4 xb = *(const float4*)&xs[r * DIM + k * 8 + 4];
                fma44(ag[r], fg, xa, xb);
                fma44(au[r], fu, xa, xb);
            }
        }
        #pragma unroll
        for (int r = 0; r < 8; ++r) {
            float g = ag[r];
            vsf[r * SINTER + j] = g / (1.f + __expf(-g)) * au[r];
        }
    }
    __syncthreads();

    const int d0 = tid, d1 = tid + 256;
    float aca[8] = {0}, acb[8] = {0};
    for (int k = 0; k < 128; ++k) {
        float fa[8], fb[8];
        ld8<BF>(wsd, (size_t)d0 * SINTER + k * 8, fa);
        ld8<BF>(wsd, (size_t)d1 * SINTER + k * 8, fb);
        #pragma unroll
        for (int r = 0; r < 8; ++r) {
            float4 v0 = *(const float4*)&vsf[r * SINTER + k * 8];
            float4 v1 = *(const float4*)&vsf[r * SINTER + k * 8 + 4];
            fma44(aca[r], fa, v0, v1);
            fma44(acb[r], fb, v0, v1);
        }
    }
    #pragma unroll
    for (int r = 0; r < 8; ++r) {
        accum[(size_t)(t0 + r) * DIM + d0] = aca[r];
        accum[(size_t)(t0 + r) * DIM + d1] = acb[r];
    }
}

__global__ __launch_bounds__(256) void k_shared(const void* xg, const void* wsg,
                                                const void* wsu, const void* wsd,
                                                const int* __restrict__ flag,
                                                float* accum) {
    if (*flag) return;   // bf16 path handled by k_shA/k_shB
    __shared__ __align__(16) float xs[8 * DIM];
    __shared__ __align__(16) float vsf[8 * SINTER];
    shared_body<false>(xg, wsg, wsu, wsd, accum, xs, vsf);
}

// ---------------- kernel RM: routed experts via MFMA (bf16 path) ----------------
__global__ __launch_bounds__(256) void k_routed_mfma(
        const u16* __restrict__ xg, const u16* __restrict__ w1,
        const u16* __restrict__ w3, const u16* __restrict__ w2t,
        const int* __restrict__ flag,
        const int* __restrict__ offsets, const int* __restrict__ counts,
        const int* __restrict__ tokl, const float* __restrict__ wgtl,
        float* __restrict__ accum) {
    if (!*flag) return;
    __shared__ __align__(16) u16 xs[16 * XP];   // 16.6 KB
    __shared__ __align__(16) u16 hs[16 * HP];   // 8.4 KB
    __shared__ int   stok[16];
    __shared__ float ssw[16];
    const int e     = blockIdx.x & 63;
    const int slice = blockIdx.x >> 6;          // 0..7
    const int tid = threadIdx.x;
    const int lane = tid & 63, w = tid >> 6;
    const int lr = lane & 15, lg = lane >> 4;
    const int n = counts[e];
    const int base = offsets[e];
    const size_t wbase  = (size_t)e * INTER * DIM;   // w1/w3 expert base
    const size_t w2base = (size_t)e * DIM * INTER;   // w2t expert base

    const f32x4 z4 = {0.f, 0.f, 0.f, 0.f};

    for (int tile = slice * 16; tile < n; tile += 128) {
        const int nt = min(16, n - tile);
        __syncthreads();  // protect stok/ssw/hs from previous iteration
        if (tid < 16) {
            int ok = tid < nt;
            stok[tid] = ok ? tokl[base + tile + tid] : tokl[base];  // pad rows: any valid token (ssw=0 kills H)
            ssw[tid]  = ok ? wgtl[base + tile + tid] : 0.f;
        }
        __syncthreads();
        for (int idx = tid; idx < 16 * 64; idx += 256) {
            int r = idx >> 6, c = idx & 63;
            *(uint4*)&xs[r * XP + c * 8] = *(const uint4*)(xg + (size_t)stok[r] * DIM + c * 8);
        }
        __syncthreads();

        // phase 1: H = silu(X W1^T) * (X W3^T) * token_weight ; wave owns inter [w*64, w*64+64)
        f32x4 a1[4] = {z4, z4, z4, z4};
        f32x4 a3[4] = {z4, z4, z4, z4};
        const int j0 = w * 64;
        for (int ks = 0; ks < 16; ++ks) {
            const int k0 = ks * 32 + lg * 8;
            bf16x8 a = *(const bf16x8*)&xs[lr * XP + k0];
            #pragma unroll
            for (int ntile = 0; ntile < 4; ++ntile) {
                const size_t row = wbase + (size_t)(j0 + ntile * 16 + lr) * DIM + k0;
                a1[ntile] = mfma16(a, *(const bf16x8*)(w1 + row), a1[ntile]);
                a3[ntile] = mfma16(a, *(const bf16x8*)(w3 + row), a3[ntile]);
            }
        }
        #pragma unroll
        for (int ntile = 0; ntile < 4; ++ntile) {
            #pragma unroll
            for (int r = 0; r < 4; ++r) {
                const int t = lg * 4 + r;
                float g = a1[ntile][r];
                float h = g / (1.f + __expf(-g)) * a3[ntile][r] * ssw[t];
                hs[t * HP + j0 + ntile * 16 + lr] = f2bf(h);
            }
        }
        __syncthreads();

        // phase 2: Y = H @ W2 (via w2t [d][i]); wave owns d in [w*128, w*128+128)
        f32x4 ay[8] = {z4, z4, z4, z4, z4, z4, z4, z4};
        for (int ks = 0; ks < 8; ++ks) {
            const int k0 = ks * 32 + lg * 8;
            bf16x8 a = *(const bf16x8*)&hs[lr * HP + k0];
            #pragma unroll
            for (int ntile = 0; ntile < 8; ++ntile) {
                const size_t row = w2base + (size_t)(w * 128 + ntile * 16 + lr) * INTER + k0;
                ay[ntile] = mfma16(a, *(const bf16x8*)(w2t + row), ay[ntile]);
            }
        }
        #pragma unroll
        for (int ntile = 0; ntile < 8; ++ntile) {
            #pragma unroll
            for (int r = 0; r < 4; ++r) {
                const int t = lg * 4 + r;
                if (t < nt)
                    atomicAdd(&accum[(size_t)stok[t] * DIM + w * 128 + ntile * 16 + lr],
                              ay[ntile][r]);
            }
        }
    }
}

// ---------------- kernel 5 (fp32 fallback): routed experts ----------------
template<bool BF>
__device__ __forceinline__ void routed_body(const void* __restrict__ xg,
                                            const void* __restrict__ w1,
                                            const void* __restrict__ w2,
                                            const void* __restrict__ w3,
                                            const int* __restrict__ offsets,
                                            const int* __restrict__ counts,
                                            const int* __restrict__ tokl,
                                            const float* __restrict__ wgtl,
                                            float* __restrict__ accum,
                                            float* xs /*16*DIM*/, float* hsf /*16*INTER*/,
                                            int* stok, float* ssw) {
    const int e = blockIdx.x & 63;
    const int slice = blockIdx.x >> 6;   // 0..3
    const int tid = threadIdx.x;
    const int n = counts[e];
    const int base = offsets[e];
    const size_t wbase = (size_t)e * INTER * DIM;

    for (int tile = slice * 16; tile < n; tile += 64) {
        const int nt = min(16, n - tile);
        __syncthreads();
        if (tid < 16) {
            int ok = tid < nt;
            stok[tid] = ok ? tokl[base + tile + tid] : 0;
            ssw[tid]  = ok ? wgtl[base + tile + tid] : 0.f;
        }
        __syncthreads();
        for (int idx = tid; idx < 16 * 64; idx += 256) {
            int r = idx >> 6, c = idx & 63;
            float* xp = &xs[r * DIM + c * 8];
            if (r < nt) {
                ld8<BF>(xg, (size_t)stok[r] * DIM + c * 8, xp);
            } else {
                #pragma unroll
                for (int q = 0; q < 8; ++q) xp[q] = 0.f;
            }
        }
        __syncthreads();

        {
            float a1[16] = {0}, a3[16] = {0};
            for (int k = 0; k < 64; ++k) {
                float f1[8], f3[8];
                ld8<BF>(w1, wbase + (size_t)tid * DIM + k * 8, f1);
                ld8<BF>(w3, wbase + (size_t)tid * DIM + k * 8, f3);
                #pragma unroll
                for (int t = 0; t < 16; ++t) {
                    float4 xa = *(const float4*)&xs[t * DIM + k * 8];
                    float4 xb = *(const float4*)&xs[t * DIM + k * 8 + 4];
                    fma44(a1[t], f1, xa, xb);
                    fma44(a3[t], f3, xa, xb);
                }
            }
            #pragma unroll
            for (int t = 0; t < 16; ++t) {
                float g = a1[t];
                hsf[t * INTER + tid] = g / (1.f + __expf(-g)) * a3[t] * ssw[t];
            }
        }
        __syncthreads();

        {
            const int d0 = 2 * tid;
            float ay0[16] = {0}, ay1[16] = {0};
            for (int i = 0; i < INTER; i += 4) {
                float b0[4], b1[4];
                #pragma unroll
                for (int ii = 0; ii < 4; ++ii)
                    ld2<BF>(w2, wbase + (size_t)(i + ii) * DIM + d0, b0[ii], b1[ii]);
                #pragma unroll
                for (int t = 0; t < 16; ++t) {
                    float4 h4 = *(const float4*)&hsf[t * INTER + i];
                    ay0[t] = fmaf(h4.x, b0[0], ay0[t]); ay0[t] = fmaf(h4.y, b0[1], ay0[t]);
                    ay0[t] = fmaf(h4.z, b0[2], ay0[t]); ay0[t] = fmaf(h4.w, b0[3], ay0[t]);
                    ay1[t] = fmaf(h4.x, b1[0], ay1[t]); ay1[t] = fmaf(h4.y, b1[1], ay1[t]);
                    ay1[t] = fmaf(h4.z, b1[2], ay1[t]); ay1[t] = fmaf(h4.w, b1[3], ay1[t]);
                }
            }
            for (int t = 0; t < nt; ++t) {
                float* dst = &accum[(size_t)stok[t] * DIM + d0];
                atomicAdd(dst, ay0[t]);
                atomicAdd(dst + 1, ay1[t]);
            }
        }
    }
}

__global__ __launch_bounds__(256) void k_routed(const void* xg, const void* w1,
                                                const void* w2, const void* w3,
                                                const int* __restrict__ flag,
                                                const int* offsets, const int* counts,
                                                const int* tokl, const float* wgtl,
                                                float* accum) {
    if (*flag) return;   // bf16 path handled by k_routed_mfma
    __shared__ __align__(16) float xs[16 * DIM];
    __shared__ __align__(16) float hsf[16 * INTER];
    __shared__ int   stok[16];
    __shared__ float ssw[16];
    routed_body<false>(xg, w1, w2, w3, offsets, counts, tokl, wgtl, accum, xs, hsf, stok, ssw);
}

// ---------------- kernel 6: fp32 accum -> output (dtype per flag) ----------------
__global__ void k_final(const float* __restrict__ accum, void* __restrict__ out,
                        const int* __restrict__ flag) {
    int i = blockIdx.x * 256 + threadIdx.x;
    float2 v = ((const float2*)accum)[i];
    if (*flag) {
        ((u32*)out)[i] = (u32)f2bf(v.x) | ((u32)f2bf(v.y) << 16);
    } else {
        ((float2*)out)[i] = v;
    }
}

extern "C" void kernel_launch(void* const* d_in, const int* in_sizes, int n_in,
                              void* d_out, int out_size, void* d_ws, size_t ws_size,
                              hipStream_t stream) {
    const void* x   = d_in[0];
    const void* wg  = d_in[1];
    const void* w1  = d_in[2];
    const void* w2  = d_in[3];
    const void* w3  = d_in[4];
    const void* wsg = d_in[5];
    const void* wsu = d_in[6];
    const void* wsd = d_in[7];

    char* ws = (char*)d_ws;
    float* accum  = (float*)ws;                              // 1024*512*4 = 2 MB
    int* counts   = (int*)(ws + (size_t)T_TOK * DIM * 4);
    int* offsets  = counts + 64;
    int* cursors  = offsets + 64;
    int* topki    = cursors + 64;                            // 6144 ints
    float* topkw  = (float*)(topki + T_TOK * TOPK);          // 6144 floats
    int* tokl     = (int*)(topkw + T_TOK * TOPK);            // 6144 ints
    float* wgtl   = (float*)(tokl + T_TOK * TOPK);           // 6144 floats
    int* flag     = (int*)(wgtl + T_TOK * TOPK);
    u16* w2t      = (u16*)(ws + ((size_t)3 << 20));          // 16 MB: [3MB, 19MB)
    u16* vbuf     = (u16*)(ws + ((size_t)19 << 20));         //  2 MB: [19MB, 21MB)

    k_probe  <<<1, 64, 0, stream>>>((const u32*)x, flag);
    k_init   <<<1, 64, 0, stream>>>(counts);
    k_router <<<T_TOK, 64, 0, stream>>>(x, wg, flag, counts, topki, topkw);
    k_prefix <<<1, 64, 0, stream>>>(counts, offsets, cursors);
    k_scatter<<<4, 256, 0, stream>>>(topki, topkw, cursors, tokl, wgtl);
    k_w2t    <<<512, 256, 0, stream>>>((const u16*)w2, w2t, flag);
    k_shA    <<<256, 256, 0, stream>>>((const u16*)x, (const u16*)wsg, (const u16*)wsu, vbuf, flag);
    k_shB    <<<512, 256, 0, stream>>>(vbuf, (const u16*)wsd, accum, flag);
    k_shared <<<128, 256, 0, stream>>>(x, wsg, wsu, wsd, flag, accum);          // fp32 fallback
    k_routed_mfma<<<512, 256, 0, stream>>>((const u16*)x, (const u16*)w1, (const u16*)w3,
                                           w2t, flag, offsets, counts, tokl, wgtl, accum);
    k_routed <<<256, 256, 0, stream>>>(x, w1, w2, w3, flag, offsets, counts, tokl, wgtl, accum); // fp32 fallback
    k_final  <<<1024, 256, 0, stream>>>(accum, d_out, flag);
}

// Round 3
// 516.186 us; speedup vs baseline: 1.1744x; 1.1744x over previous
//
#include <hip/hip_runtime.h>
#include <math.h>

// Problem constants
#define T_TOK 1024
#define DIM 512
#define INTER 256
#define SINTER 1024
#define NEXP 64
#define TOPK 6

typedef unsigned short u16;
typedef unsigned int u32;
typedef short bf16x8 __attribute__((ext_vector_type(8)));   // 8 bf16 (4 VGPRs)
typedef float f32x4  __attribute__((ext_vector_type(4)));   // MFMA 16x16 accumulator

__device__ __forceinline__ float bflo(u32 u) { return __uint_as_float(u << 16); }
__device__ __forceinline__ float bfhi(u32 u) { return __uint_as_float(u & 0xffff0000u); }

__device__ __forceinline__ u16 f2bf(float f) {
    u32 u = __float_as_uint(f);
    return (u16)((u + 0x7fffu + ((u >> 16) & 1u)) >> 16);  // RNE
}

__device__ __forceinline__ f32x4 mfma16(bf16x8 a, bf16x8 b, f32x4 c) {
    return __builtin_amdgcn_mfma_f32_16x16x32_bf16(a, b, c, 0, 0, 0);
}

// split fp32 -> (hi bf16, lo bf16): v ~= vh + vl, combined err ~2^-16|v|
__device__ __forceinline__ void split1(float v, u16& h, u16& l) {
    u32 u = __float_as_uint(v);
    u32 hb = u & 0xffff0000u;
    float r = v - __uint_as_float(hb);
    h = (u16)(hb >> 16);
    l = (u16)(__float_as_uint(r) >> 16);
}

// split 8 consecutive fp32 (32B-aligned) into hi/lo bf16x8 packed as uint4
__device__ __forceinline__ void split8u(const float* __restrict__ s, uint4& H, uint4& L) {
    const uint4* q = (const uint4*)s;
    uint4 A = q[0], B = q[1];
    u32 wv[8] = {A.x, A.y, A.z, A.w, B.x, B.y, B.z, B.w};
    u32 hp[4], lp[4];
    #pragma unroll
    for (int i = 0; i < 4; ++i) {
        u32 u0 = wv[2*i], u1 = wv[2*i+1];
        u32 h0 = u0 & 0xffff0000u, h1 = u1 & 0xffff0000u;
        float r0 = __uint_as_float(u0) - __uint_as_float(h0);
        float r1 = __uint_as_float(u1) - __uint_as_float(h1);
        hp[i] = (h0 >> 16) | h1;
        lp[i] = (__float_as_uint(r0) >> 16) | (__float_as_uint(r1) & 0xffff0000u);
    }
    H.x = hp[0]; H.y = hp[1]; H.z = hp[2]; H.w = hp[3];
    L.x = lp[0]; L.y = lp[1]; L.z = lp[2]; L.w = lp[3];
}

__device__ __forceinline__ void split8(const float* __restrict__ s, bf16x8& h, bf16x8& l) {
    uint4 H, L;
    split8u(s, H, L);
    h = *(bf16x8*)&H;
    l = *(bf16x8*)&L;
}

// load 8 consecutive elements (idx must be a multiple of 8) as floats
template<bool BF>
__device__ __forceinline__ void ld8(const void* p, size_t idx, float* f) {
    if (BF) {
        uint4 u = *(const uint4*)((const u16*)p + idx);
        f[0] = bflo(u.x); f[1] = bfhi(u.x);
        f[2] = bflo(u.y); f[3] = bfhi(u.y);
        f[4] = bflo(u.z); f[5] = bfhi(u.z);
        f[6] = bflo(u.w); f[7] = bfhi(u.w);
    } else {
        const float4* q = (const float4*)((const float*)p + idx);
        float4 a = q[0], b = q[1];
        f[0] = a.x; f[1] = a.y; f[2] = a.z; f[3] = a.w;
        f[4] = b.x; f[5] = b.y; f[6] = b.z; f[7] = b.w;
    }
}

// load 2 consecutive elements (idx even)
template<bool BF>
__device__ __forceinline__ void ld2(const void* p, size_t idx, float& a, float& b) {
    if (BF) { u32 w = *(const u32*)((const u16*)p + idx); a = bflo(w); b = bfhi(w); }
    else    { float2 v = *(const float2*)((const float*)p + idx); a = v.x; b = v.y; }
}

__device__ __forceinline__ void fma44(float& acc, const float* f, const float4& a, const float4& b) {
    acc = fmaf(f[0], a.x, acc); acc = fmaf(f[1], a.y, acc);
    acc = fmaf(f[2], a.z, acc); acc = fmaf(f[3], a.w, acc);
    acc = fmaf(f[4], b.x, acc); acc = fmaf(f[5], b.y, acc);
    acc = fmaf(f[6], b.z, acc); acc = fmaf(f[7], b.w, acc);
}

// ---------------- kernel P: dtype probe ----------------
__global__ void k_probe(const u32* __restrict__ xw, int* __restrict__ flag) {
    int cnt = 0;
    #pragma unroll
    for (int i = 0; i < 8; ++i) {
        u32 u = xw[threadIdx.x * 8 + i];
        u32 e = (u >> 7) & 0xffu;           // exponent of low-half-as-bf16
        cnt += (e >= 110 && e <= 140) ? 1 : 0;
    }
    #pragma unroll
    for (int off = 32; off; off >>= 1) cnt += __shfl_xor(cnt, off);
    if (threadIdx.x == 0) flag[0] = (cnt > 256) ? 1 : 0;
}

// ---------------- kernel 0: zero the expert counters ----------------
__global__ void k_init(int* counts) {
    counts[threadIdx.x] = 0;
}

// ---------------- kernel 1: router (dual dtype) ----------------
template<bool BF>
__device__ __forceinline__ void router_body(const void* __restrict__ xg,
                                            const void* __restrict__ wg,
                                            int* __restrict__ counts,
                                            int* __restrict__ topki,
                                            float* __restrict__ topkw,
                                            float* xs, float* svals, int* sidx) {
    const int t = blockIdx.x;
    const int lane = threadIdx.x;

    ld8<BF>(xg, (size_t)t * DIM + lane * 8, &xs[lane * 8]);
    __syncthreads();

    float acc = 0.f;
    for (int k = 0; k < 64; ++k) {
        float f[8]; ld8<BF>(wg, (size_t)lane * DIM + k * 8, f);
        float4 xa = *(const float4*)&xs[k * 8];
        float4 xb = *(const float4*)&xs[k * 8 + 4];
        fma44(acc, f, xa, xb);
    }

    float my = acc;
    for (int s = 0; s < TOPK; ++s) {
        float v = my; int id = lane;
        #pragma unroll
        for (int off = 32; off; off >>= 1) {
            float ov = __shfl_xor(v, off);
            int   oi = __shfl_xor(id, off);
            if (ov > v || (ov == v && oi < id)) { v = ov; id = oi; }
        }
        if (lane == 0) { svals[s] = v; sidx[s] = id; }
        if (lane == id) my = -INFINITY;
    }
    __syncthreads();
    if (lane == 0) {
        float m = svals[0], sum = 0.f, w[TOPK];
        #pragma unroll
        for (int s = 0; s < TOPK; ++s) { w[s] = __expf(svals[s] - m); sum += w[s]; }
        float inv = 1.f / sum;
        #pragma unroll
        for (int s = 0; s < TOPK; ++s) {
            int e = sidx[s];
            topki[t * TOPK + s] = e;
            topkw[t * TOPK + s] = w[s] * inv;
            atomicAdd(&counts[e], 1);
        }
    }
}

__global__ __launch_bounds__(64) void k_router(const void* xg, const void* wg,
                                               const int* __restrict__ flag,
                                               int* counts, int* topki, float* topkw) {
    __shared__ __align__(16) float xs[DIM];
    __shared__ float svals[TOPK];
    __shared__ int sidx[TOPK];
    if (*flag) router_body<true >(xg, wg, counts, topki, topkw, xs, svals, sidx);
    else       router_body<false>(xg, wg, counts, topki, topkw, xs, svals, sidx);
}

// ---------------- kernel 2: prefix sum over 64 experts ----------------
__global__ void k_prefix(const int* __restrict__ counts, int* __restrict__ offsets,
                         int* __restrict__ cursors) {
    if (threadIdx.x == 0) {
        int acc = 0;
        for (int e = 0; e < NEXP; ++e) { offsets[e] = acc; cursors[e] = acc; acc += counts[e]; }
    }
}

// ---------------- kernel 3: scatter tokens into expert buckets ----------------
__global__ void k_scatter(const int* __restrict__ topki, const float* __restrict__ topkw,
                          int* __restrict__ cursors, int* __restrict__ tokl,
                          float* __restrict__ wgtl) {
    int t = blockIdx.x * 256 + threadIdx.x;
    #pragma unroll
    for (int s = 0; s < TOPK; ++s) {
        int e = topki[t * TOPK + s];
        float w = topkw[t * TOPK + s];
        int pos = atomicAdd(&cursors[e], 1);
        tokl[pos] = t;
        wgtl[pos] = w;
    }
}

// ============== fp32 path (flag==0): split-bf16 MFMA kernels ==============

// ---------------- kernel W: transpose+split w2 [e][i][d] -> hi/lo [e][d][i] ----------------
__global__ __launch_bounds__(256) void k_w2ts(const float* __restrict__ w2,
                                              u16* __restrict__ w2th,
                                              u16* __restrict__ w2tl,
                                              const int* __restrict__ flag) {
    if (*flag) return;
    __shared__ u32 lt[128][65];              // packed hi<<16|lo; pad 65 breaks conflicts
    const int e  = blockIdx.x >> 4;
    const int ic = (blockIdx.x >> 3) & 1;    // i-chunk of 128
    const int dc = blockIdx.x & 7;           // d-chunk of 64
    const int tid = threadIdx.x;
    const float* src = w2 + (size_t)e * INTER * DIM + (size_t)(ic * 128) * DIM + dc * 64;
    #pragma unroll
    for (int p = 0; p < 8; ++p) {
        int f = p * 256 + tid;               // 0..2047 float4s
        int i = f >> 4, dq = f & 15;
        float4 v = *(const float4*)(src + (size_t)i * DIM + dq * 4);
        float vv[4] = {v.x, v.y, v.z, v.w};
        #pragma unroll
        for (int j = 0; j < 4; ++j) {
            u32 u = __float_as_uint(vv[j]);
            u32 hb = u & 0xffff0000u;
            float r = vv[j] - __uint_as_float(hb);
            lt[i][dq * 4 + j] = hb | (__float_as_uint(r) >> 16);
        }
    }
    __syncthreads();
    const int dl = tid & 63, q = tid >> 6;   // wave q handles i-chunk q*32
    size_t rb = ((size_t)e * DIM + dc * 64 + dl) * INTER + ic * 128 + q * 32;
    #pragma unroll
    for (int s = 0; s < 4; ++s) {
        u32 h2[4], l2[4];
        #pragma unroll
        for (int m = 0; m < 4; ++m) {
            u32 p0 = lt[q * 32 + s * 8 + m * 2][dl];
            u32 p1 = lt[q * 32 + s * 8 + m * 2 + 1][dl];
            h2[m] = (p0 >> 16) | (p1 & 0xffff0000u);
            l2[m] = (p0 & 0xffffu) | (p1 << 16);
        }
        uint4 Hv = {h2[0], h2[1], h2[2], h2[3]};
        uint4 Lv = {l2[0], l2[1], l2[2], l2[3]};
        *(uint4*)(w2th + rb + s * 8) = Hv;
        *(uint4*)(w2tl + rb + s * 8) = Lv;
    }
}

// ---------------- kernel SA3: shared expert up/gate, V = silu(X Wsg^T)*(X Wsu^T) ----------------
__global__ __launch_bounds__(256) void k_shA3(const float* __restrict__ xg,
                                              const float* __restrict__ wsgf,
                                              const float* __restrict__ wsuf,
                                              u16* __restrict__ vh, u16* __restrict__ vl,
                                              const int* __restrict__ flag) {
    if (*flag) return;
    __shared__ __align__(16) u16 xsh[16 * 512], xsl[16 * 512];   // 32 KB (XOR-swizzled)
    __shared__ __align__(16) u16 vsh[16 * 256], vsl[16 * 256];   // 16 KB
    const int tt = blockIdx.x >> 2;          // token tile (16 rows)
    const int sc = blockIdx.x & 3;           // sinter chunk of 256
    const int tid = threadIdx.x;
    const int w = tid >> 6, lane = tid & 63;
    const int lr = lane & 15, lg = lane >> 4;

    for (int idx = tid; idx < 16 * 64; idx += 256) {
        int r = idx >> 6, c = idx & 63;
        int off = r * 1024 + ((c * 16) ^ ((r & 7) << 4));
        uint4 Hq, Lq;
        split8u(xg + (size_t)(tt * 16 + r) * DIM + c * 8, Hq, Lq);
        *(uint4*)((char*)xsh + off) = Hq;
        *(uint4*)((char*)xsl + off) = Lq;
    }
    __syncthreads();

    const f32x4 z4 = {0.f, 0.f, 0.f, 0.f};
    f32x4 ag[4] = {z4, z4, z4, z4};
    f32x4 au[4] = {z4, z4, z4, z4};
    const int j0 = sc * 256 + w * 64;
    for (int ks = 0; ks < 16; ++ks) {
        const int k0 = ks * 32 + lg * 8;
        const int xoff = lr * 1024 + ((k0 * 2) ^ ((lr & 7) << 4));
        bf16x8 ah = *(const bf16x8*)((const char*)xsh + xoff);
        bf16x8 al = *(const bf16x8*)((const char*)xsl + xoff);
        #pragma unroll
        for (int q = 0; q < 4; ++q) {
            const size_t row = (size_t)(j0 + q * 16 + lr) * DIM + k0;
            bf16x8 bh, bl;
            split8(wsgf + row, bh, bl);
            ag[q] = mfma16(ah, bh, ag[q]);
            ag[q] = mfma16(ah, bl, ag[q]);
            ag[q] = mfma16(al, bh, ag[q]);
            split8(wsuf + row, bh, bl);
            au[q] = mfma16(ah, bh, au[q]);
            au[q] = mfma16(ah, bl, au[q]);
            au[q] = mfma16(al, bh, au[q]);
        }
    }
    #pragma unroll
    for (int q = 0; q < 4; ++q) {
        #pragma unroll
        for (int r = 0; r < 4; ++r) {
            const int t = lg * 4 + r;
            float g = ag[q][r];
            float v = g / (1.f + __expf(-g)) * au[q][r];
            u16 h16, l16; split1(v, h16, l16);
            const int col = w * 64 + q * 16 + lr;              // 0..255 within chunk
            const int off = t * 512 + ((col * 2) ^ ((t & 7) << 4));
            *(u16*)((char*)vsh + off) = h16;
            *(u16*)((char*)vsl + off) = l16;
        }
    }
    __syncthreads();
    #pragma unroll
    for (int p = 0; p < 2; ++p) {
        int idx = p * 256 + tid;
        int r = idx >> 5, c = idx & 31;
        int off = r * 512 + ((c * 16) ^ ((r & 7) << 4));
        size_t g = (size_t)(tt * 16 + r) * SINTER + sc * 256 + c * 8;
        *(uint4*)(vh + g) = *(const uint4*)((const char*)vsh + off);
        *(uint4*)(vl + g) = *(const uint4*)((const char*)vsl + off);
    }
}

// ---------------- kernel SB3: shared expert down, accum = V @ Wsd^T ----------------
__global__ __launch_bounds__(256) void k_shB3(const u16* __restrict__ vh,
                                              const u16* __restrict__ vl,
                                              const float* __restrict__ wsdf,
                                              float* __restrict__ accum,
                                              const int* __restrict__ flag) {
    if (*flag) return;
    const int tt = blockIdx.x >> 3;          // token tile (16)
    const int dc = blockIdx.x & 7;           // 64-dim chunk
    const int w = threadIdx.x >> 6, lane = threadIdx.x & 63;
    const int lr = lane & 15, lg = lane >> 4;
    const int d0 = dc * 64 + w * 16;
    const u16* vhrow = vh + (size_t)(tt * 16 + lr) * SINTER;
    const u16* vlrow = vl + (size_t)(tt * 16 + lr) * SINTER;
    const float* wrow = wsdf + (size_t)(d0 + lr) * SINTER;
    f32x4 acc = {0.f, 0.f, 0.f, 0.f};
    for (int ks = 0; ks < 32; ++ks) {
        const int k0 = ks * 32 + lg * 8;
        bf16x8 avh = *(const bf16x8*)(vhrow + k0);
        bf16x8 avl = *(const bf16x8*)(vlrow + k0);
        bf16x8 bh, bl;
        split8(wrow + k0, bh, bl);
        acc = mfma16(avh, bh, acc);
        acc = mfma16(avh, bl, acc);
        acc = mfma16(avl, bh, acc);
    }
    #pragma unroll
    for (int r = 0; r < 4; ++r)
        accum[(size_t)(tt * 16 + lg * 4 + r) * DIM + d0 + lr] = acc[r];
}

// ---------------- kernel RM3: routed experts, split-bf16 MFMA ----------------
__global__ __launch_bounds__(256) void k_routed_mfma3(
        const float* __restrict__ xg,
        const float* __restrict__ w1f, const float* __restrict__ w3f,
        const u16* __restrict__ w2th, const u16* __restrict__ w2tl,
        const int* __restrict__ flag,
        const int* __restrict__ offsets, const int* __restrict__ counts,
        const int* __restrict__ tokl, const float* __restrict__ wgtl,
        float* __restrict__ accum) {
    if (*flag) return;
    __shared__ __align__(16) u16 xsh[16 * 512], xsl[16 * 512];   // 32 KB
    __shared__ __align__(16) u16 hsh[16 * 256], hsl[16 * 256];   // 16 KB
    __shared__ int   stok[16];
    __shared__ float ssw[16];
    const int e     = blockIdx.x & 63;
    const int slice = blockIdx.x >> 6;       // 0..7
    const int tid  = threadIdx.x;
    const int lane = tid & 63, w = tid >> 6;
    const int lr = lane & 15, lg = lane >> 4;
    const int n = counts[e];
    const int base = offsets[e];
    const size_t wbase  = (size_t)e * INTER * DIM;   // w1/w3 expert base (fp32)
    const size_t w2base = (size_t)e * DIM * INTER;   // w2t expert base (bf16 planes)
    const f32x4 z4 = {0.f, 0.f, 0.f, 0.f};

    for (int tile = slice * 16; tile < n; tile += 128) {
        const int cnt = min(16, n - tile);
        __syncthreads();  // protect stok/ssw/xs/hs from previous iteration
        if (tid < 16) {
            int ok = tid < cnt;
            stok[tid] = ok ? tokl[base + tile + tid] : tokl[base];  // pad: valid token, ssw=0
            ssw[tid]  = ok ? wgtl[base + tile + tid] : 0.f;
        }
        __syncthreads();
        for (int idx = tid; idx < 16 * 64; idx += 256) {
            int r = idx >> 6, c = idx & 63;
            int off = r * 1024 + ((c * 16) ^ ((r & 7) << 4));
            uint4 Hq, Lq;
            split8u(xg + (size_t)stok[r] * DIM + c * 8, Hq, Lq);
            *(uint4*)((char*)xsh + off) = Hq;
            *(uint4*)((char*)xsl + off) = Lq;
        }
        __syncthreads();

        // phase 1: H = silu(X W1^T) * (X W3^T) * token_weight ; wave owns inter [w*64,+64)
        f32x4 a1[4] = {z4, z4, z4, z4};
        f32x4 a3[4] = {z4, z4, z4, z4};
        const int j0 = w * 64;
        for (int ks = 0; ks < 16; ++ks) {
            const int k0 = ks * 32 + lg * 8;
            const int xoff = lr * 1024 + ((k0 * 2) ^ ((lr & 7) << 4));
            bf16x8 ah = *(const bf16x8*)((const char*)xsh + xoff);
            bf16x8 al = *(const bf16x8*)((const char*)xsl + xoff);
            #pragma unroll
            for (int q = 0; q < 4; ++q) {
                const size_t row = wbase + (size_t)(j0 + q * 16 + lr) * DIM + k0;
                bf16x8 bh, bl;
                split8(w1f + row, bh, bl);
                a1[q] = mfma16(ah, bh, a1[q]);
                a1[q] = mfma16(ah, bl, a1[q]);
                a1[q] = mfma16(al, bh, a1[q]);
                split8(w3f + row, bh, bl);
                a3[q] = mfma16(ah, bh, a3[q]);
                a3[q] = mfma16(ah, bl, a3[q]);
                a3[q] = mfma16(al, bh, a3[q]);
            }
        }
        #pragma unroll
        for (int q = 0; q < 4; ++q) {
            #pragma unroll
            for (int r = 0; r < 4; ++r) {
                const int t = lg * 4 + r;
                float g = a1[q][r];
                float h = g / (1.f + __expf(-g)) * a3[q][r] * ssw[t];
                u16 hh16, hl16; split1(h, hh16, hl16);
                const int col = j0 + q * 16 + lr;
                const int off = t * 512 + ((col * 2) ^ ((t & 7) << 4));
                *(u16*)((char*)hsh + off) = hh16;
                *(u16*)((char*)hsl + off) = hl16;
            }
        }
        __syncthreads();

        // phase 2: Y = H @ W2 (via w2t hi/lo planes); wave owns d in [w*128,+128)
        f32x4 ay[8] = {z4, z4, z4, z4, z4, z4, z4, z4};
        for (int ks = 0; ks < 8; ++ks) {
            const int k0 = ks * 32 + lg * 8;
            const int hoff = lr * 512 + ((k0 * 2) ^ ((lr & 7) << 4));
            bf16x8 ah = *(const bf16x8*)((const char*)hsh + hoff);
            bf16x8 al = *(const bf16x8*)((const char*)hsl + hoff);
            #pragma unroll
            for (int q = 0; q < 8; ++q) {
                const size_t row = w2base + (size_t)(w * 128 + q * 16 + lr) * INTER + k0;
                bf16x8 bh = *(const bf16x8*)(w2th + row);
                bf16x8 bl = *(const bf16x8*)(w2tl + row);
                ay[q] = mfma16(ah, bh, ay[q]);
                ay[q] = mfma16(ah, bl, ay[q]);
                ay[q] = mfma16(al, bh, ay[q]);
            }
        }
        #pragma unroll
        for (int q = 0; q < 8; ++q) {
            #pragma unroll
            for (int r = 0; r < 4; ++r) {
                const int t = lg * 4 + r;
                if (t < cnt)
                    atomicAdd(&accum[(size_t)stok[t] * DIM + w * 128 + q * 16 + lr],
                              ay[q][r]);
            }
        }
    }
}

// ============== legacy VALU kernels (bf16 inputs, or small-workspace fallback) ==============

template<bool BF>
__device__ __forceinline__ void shared_body(const void* __restrict__ xg,
                                            const void* __restrict__ wsg,
                                            const void* __restrict__ wsu,
                                            const void* __restrict__ wsd,
                                            float* __restrict__ accum,
                                            float* xs /*8*DIM*/, float* vsf /*8*SINTER*/) {
    const int t0 = blockIdx.x * 8;
    const int tid = threadIdx.x;

    for (int idx = tid; idx < 8 * 64; idx += 256) {
        int r = idx >> 6, c = idx & 63;
        ld8<BF>(xg, (size_t)(t0 + r) * DIM + c * 8, &xs[r * DIM + c * 8]);
    }
    __syncthreads();

    for (int jc = 0; jc < 4; ++jc) {
        int j = jc * 256 + tid;
        float ag[8] = {0}, au[8] = {0};
        for (int k = 0; k < 64; ++k) {
            float fg[8], fu[8];
            ld8<BF>(wsg, (size_t)j * DIM + k * 8, fg);
            ld8<BF>(wsu, (size_t)j * DIM + k * 8, fu);
            #pragma unroll
            for (int r = 0; r < 8; ++r) {
                float4 xa = *(const float4*)&xs[r * DIM + k * 8];
                float4 xb = *(const float4*)&xs[r * DIM + k * 8 + 4];
                fma44(ag[r], fg, xa, xb);
                fma44(au[r], fu, xa, xb);
            }
        }
        #pragma unroll
        for (int r = 0; r < 8; ++r) {
            float g = ag[r];
            vsf[r * SINTER + j] = g / (1.f + __expf(-g)) * au[r];
        }
    }
    __syncthreads();

    const int d0 = tid, d1 = tid + 256;
    float aca[8] = {0}, acb[8] = {0};
    for (int k = 0; k < 128; ++k) {
        float fa[8], fb[8];
        ld8<BF>(wsd, (size_t)d0 * SINTER + k * 8, fa);
        ld8<BF>(wsd, (size_t)d1 * SINTER + k * 8, fb);
        #pragma unroll
        for (int r = 0; r < 8; ++r) {
            float4 v0 = *(const float4*)&vsf[r * SINTER + k * 8];
            float4 v1 = *(const float4*)&vsf[r * SINTER + k * 8 + 4];
            fma44(aca[r], fa, v0, v1);
            fma44(acb[r], fb, v0, v1);
        }
    }
    #pragma unroll
    for (int r = 0; r < 8; ++r) {
        accum[(size_t)(t0 + r) * DIM + d0] = aca[r];
        accum[(size_t)(t0 + r) * DIM + d1] = acb[r];
    }
}

__global__ __launch_bounds__(256) void k_shared(const void* xg, const void* wsg,
                                                const void* wsu, const void* wsd,
                                                const int* __restrict__ flag,
                                                float* accum, int bfonly) {
    if (bfonly && !*flag) return;   // fp32 handled by k_shA3/k_shB3
    __shared__ __align__(16) float xs[8 * DIM];
    __shared__ __align__(16) float vsf[8 * SINTER];
    if (*flag) shared_body<true >(xg, wsg, wsu, wsd, accum, xs, vsf);
    else       shared_body<false>(xg, wsg, wsu, wsd, accum, xs, vsf);
}

template<bool BF>
__device__ __forceinline__ void routed_body(const void* __restrict__ xg,
                                            const void* __restrict__ w1,
                                            const void* __restrict__ w2,
                                            const void* __restrict__ w3,
                                            const int* __restrict__ offsets,
                                            const int* __restrict__ counts,
                                            const int* __restrict__ tokl,
                                            const float* __restrict__ wgtl,
                                            float* __restrict__ accum,
                                            float* xs /*16*DIM*/, float* hsf /*16*INTER*/,
                                            int* stok, float* ssw) {
    const int e = blockIdx.x & 63;
    const int slice = blockIdx.x >> 6;   // 0..3
    const int tid = threadIdx.x;
    const int n = counts[e];
    const int base = offsets[e];
    const size_t wbase = (size_t)e * INTER * DIM;

    for (int tile = slice * 16; tile < n; tile += 64) {
        const int nt = min(16, n - tile);
        __syncthreads();
        if (tid < 16) {
            int ok = tid < nt;
            stok[tid] = ok ? tokl[base + tile + tid] : 0;
            ssw[tid]  = ok ? wgtl[base + tile + tid] : 0.f;
        }
        __syncthreads();
        for (int idx = tid; idx < 16 * 64; idx += 256) {
            int r = idx >> 6, c = idx & 63;
            float* xp = &xs[r * DIM + c * 8];
            if (r < nt) {
                ld8<BF>(xg, (size_t)stok[r] * DIM + c * 8, xp);
            } else {
                #pragma unroll
                for (int q = 0; q < 8; ++q) xp[q] = 0.f;
            }
        }
        __syncthreads();

        {
            float a1[16] = {0}, a3[16] = {0};
            for (int k = 0; k < 64; ++k) {
                float f1[8], f3[8];
                ld8<BF>(w1, wbase + (size_t)tid * DIM + k * 8, f1);
                ld8<BF>(w3, wbase + (size_t)tid * DIM + k * 8, f3);
                #pragma unroll
                for (int t = 0; t < 16; ++t) {
                    float4 xa = *(const float4*)&xs[t * DIM + k * 8];
                    float4 xb = *(const float4*)&xs[t * DIM + k * 8 + 4];
                    fma44(a1[t], f1, xa, xb);
                    fma44(a3[t], f3, xa, xb);
                }
            }
            #pragma unroll
            for (int t = 0; t < 16; ++t) {
                float g = a1[t];
                hsf[t * INTER + tid] = g / (1.f + __expf(-g)) * a3[t] * ssw[t];
            }
        }
        __syncthreads();

        {
            const int d0 = 2 * tid;
            float ay0[16] = {0}, ay1[16] = {0};
            for (int i = 0; i < INTER; i += 4) {
                float b0[4], b1[4];
                #pragma unroll
                for (int ii = 0; ii < 4; ++ii)
                    ld2<BF>(w2, wbase + (size_t)(i + ii) * DIM + d0, b0[ii], b1[ii]);
                #pragma unroll
                for (int t = 0; t < 16; ++t) {
                    float4 h4 = *(const float4*)&hsf[t * INTER + i];
                    ay0[t] = fmaf(h4.x, b0[0], ay0[t]); ay0[t] = fmaf(h4.y, b0[1], ay0[t]);
                    ay0[t] = fmaf(h4.z, b0[2], ay0[t]); ay0[t] = fmaf(h4.w, b0[3], ay0[t]);
                    ay1[t] = fmaf(h4.x, b1[0], ay1[t]); ay1[t] = fmaf(h4.y, b1[1], ay1[t]);
                    ay1[t] = fmaf(h4.z, b1[2], ay1[t]); ay1[t] = fmaf(h4.w, b1[3], ay1[t]);
                }
            }
            for (int t = 0; t < nt; ++t) {
                float* dst = &accum[(size_t)stok[t] * DIM + d0];
                atomicAdd(dst, ay0[t]);
                atomicAdd(dst + 1, ay1[t]);
            }
        }
    }
}

__global__ __launch_bounds__(256) void k_routed(const void* xg, const void* w1,
                                                const void* w2, const void* w3,
                                                const int* __restrict__ flag,
                                                const int* offsets, const int* counts,
                                                const int* tokl, const float* wgtl,
                                                float* accum, int bfonly) {
    if (bfonly && !*flag) return;   // fp32 handled by k_routed_mfma3
    __shared__ __align__(16) float xs[16 * DIM];
    __shared__ __align__(16) float hsf[16 * INTER];
    __shared__ int   stok[16];
    __shared__ float ssw[16];
    if (*flag) routed_body<true >(xg, w1, w2, w3, offsets, counts, tokl, wgtl, accum, xs, hsf, stok, ssw);
    else       routed_body<false>(xg, w1, w2, w3, offsets, counts, tokl, wgtl, accum, xs, hsf, stok, ssw);
}

// ---------------- kernel 6: fp32 accum -> output (dtype per flag) ----------------
__global__ void k_final(const float* __restrict__ accum, void* __restrict__ out,
                        const int* __restrict__ flag) {
    int i = blockIdx.x * 256 + threadIdx.x;
    float2 v = ((const float2*)accum)[i];
    if (*flag) {
        ((u32*)out)[i] = (u32)f2bf(v.x) | ((u32)f2bf(v.y) << 16);
    } else {
        ((float2*)out)[i] = v;
    }
}

extern "C" void kernel_launch(void* const* d_in, const int* in_sizes, int n_in,
                              void* d_out, int out_size, void* d_ws, size_t ws_size,
                              hipStream_t stream) {
    const void* x   = d_in[0];
    const void* wg  = d_in[1];
    const void* w1  = d_in[2];
    const void* w2  = d_in[3];
    const void* w3  = d_in[4];
    const void* wsg = d_in[5];
    const void* wsu = d_in[6];
    const void* wsd = d_in[7];

    char* ws = (char*)d_ws;
    float* accum  = (float*)ws;                              // [0, 2MB)
    char* ctrl    = ws + ((size_t)2 << 20);
    int* counts   = (int*)ctrl;
    int* offsets  = counts + 64;
    int* cursors  = offsets + 64;
    int* topki    = cursors + 64;                            // 6144 ints
    float* topkw  = (float*)(topki + T_TOK * TOPK);          // 6144 floats
    int* tokl     = (int*)(topkw + T_TOK * TOPK);            // 6144 ints
    float* wgtl   = (float*)(tokl + T_TOK * TOPK);           // 6144 floats
    int* flag     = (int*)(wgtl + T_TOK * TOPK);
    u16* w2th = (u16*)(ws + ((size_t)3  << 20));             // 16 MB [3,19)
    u16* w2tl = (u16*)(ws + ((size_t)19 << 20));             // 16 MB [19,35)
    u16* vh   = (u16*)(ws + ((size_t)35 << 20));             //  2 MB [35,37)
    u16* vl   = (u16*)(ws + ((size_t)37 << 20));             //  2 MB [37,39)
    const bool fast = ws_size >= ((size_t)39 << 20);

    k_probe  <<<1, 64, 0, stream>>>((const u32*)x, flag);
    k_init   <<<1, 64, 0, stream>>>(counts);
    k_router <<<T_TOK, 64, 0, stream>>>(x, wg, flag, counts, topki, topkw);
    k_prefix <<<1, 64, 0, stream>>>(counts, offsets, cursors);
    k_scatter<<<4, 256, 0, stream>>>(topki, topkw, cursors, tokl, wgtl);

    if (fast) {
        k_w2ts   <<<1024, 256, 0, stream>>>((const float*)w2, w2th, w2tl, flag);
        k_shA3   <<<256, 256, 0, stream>>>((const float*)x, (const float*)wsg,
                                           (const float*)wsu, vh, vl, flag);
        k_shB3   <<<512, 256, 0, stream>>>(vh, vl, (const float*)wsd, accum, flag);
        k_routed_mfma3<<<512, 256, 0, stream>>>((const float*)x, (const float*)w1,
                                                (const float*)w3, w2th, w2tl, flag,
                                                offsets, counts, tokl, wgtl, accum);
        // bf16-input fallback (no-ops when flag==0)
        k_shared <<<128, 256, 0, stream>>>(x, wsg, wsu, wsd, flag, accum, 1);
        k_routed <<<256, 256, 0, stream>>>(x, w1, w2, w3, flag, offsets, counts, tokl, wgtl, accum, 1);
    } else {
        // small workspace: legacy VALU path for both dtypes
        k_shared <<<128, 256, 0, stream>>>(x, wsg, wsu, wsd, flag, accum, 0);
        k_routed <<<256, 256, 0, stream>>>(x, w1, w2, w3, flag, offsets, counts, tokl, wgtl, accum, 0);
    }
    k_final  <<<1024, 256, 0, stream>>>(accum, d_out, flag);
}

// Round 4
// 462.162 us; speedup vs baseline: 1.3117x; 1.1169x over previous
//
#include <hip/hip_runtime.h>
#include <math.h>

// Problem constants
#define T_TOK 1024
#define DIM 512
#define INTER 256
#define SINTER 1024
#define NEXP 64
#define TOPK 6

typedef unsigned short u16;
typedef unsigned int u32;
typedef short bf16x8 __attribute__((ext_vector_type(8)));   // 8 bf16 (4 VGPRs)
typedef float f32x4  __attribute__((ext_vector_type(4)));   // MFMA 16x16 accumulator

__device__ __forceinline__ float bflo(u32 u) { return __uint_as_float(u << 16); }
__device__ __forceinline__ float bfhi(u32 u) { return __uint_as_float(u & 0xffff0000u); }

__device__ __forceinline__ u16 f2bf(float f) {
    u32 u = __float_as_uint(f);
    return (u16)((u + 0x7fffu + ((u >> 16) & 1u)) >> 16);  // RNE
}

__device__ __forceinline__ f32x4 mfma16(bf16x8 a, bf16x8 b, f32x4 c) {
    return __builtin_amdgcn_mfma_f32_16x16x32_bf16(a, b, c, 0, 0, 0);
}

// split fp32 -> (hi bf16, lo bf16): v ~= vh + vl, combined err ~2^-16|v|
__device__ __forceinline__ void split1(float v, u16& h, u16& l) {
    u32 u = __float_as_uint(v);
    u32 hb = u & 0xffff0000u;
    float r = v - __uint_as_float(hb);
    h = (u16)(hb >> 16);
    l = (u16)(__float_as_uint(r) >> 16);
}

// split 8 consecutive fp32 (32B-aligned) into hi/lo bf16x8 packed as uint4
__device__ __forceinline__ void split8u(const float* __restrict__ s, uint4& H, uint4& L) {
    const uint4* q = (const uint4*)s;
    uint4 A = q[0], B = q[1];
    u32 wv[8] = {A.x, A.y, A.z, A.w, B.x, B.y, B.z, B.w};
    u32 hp[4], lp[4];
    #pragma unroll
    for (int i = 0; i < 4; ++i) {
        u32 u0 = wv[2*i], u1 = wv[2*i+1];
        u32 h0 = u0 & 0xffff0000u, h1 = u1 & 0xffff0000u;
        float r0 = __uint_as_float(u0) - __uint_as_float(h0);
        float r1 = __uint_as_float(u1) - __uint_as_float(h1);
        hp[i] = (h0 >> 16) | h1;
        lp[i] = (__float_as_uint(r0) >> 16) | (__float_as_uint(r1) & 0xffff0000u);
    }
    H.x = hp[0]; H.y = hp[1]; H.z = hp[2]; H.w = hp[3];
    L.x = lp[0]; L.y = lp[1]; L.z = lp[2]; L.w = lp[3];
}

__device__ __forceinline__ void split8(const float* __restrict__ s, bf16x8& h, bf16x8& l) {
    uint4 H, L;
    split8u(s, H, L);
    h = *(bf16x8*)&H;
    l = *(bf16x8*)&L;
}

// load 8 consecutive elements (idx must be a multiple of 8) as floats
template<bool BF>
__device__ __forceinline__ void ld8(const void* p, size_t idx, float* f) {
    if (BF) {
        uint4 u = *(const uint4*)((const u16*)p + idx);
        f[0] = bflo(u.x); f[1] = bfhi(u.x);
        f[2] = bflo(u.y); f[3] = bfhi(u.y);
        f[4] = bflo(u.z); f[5] = bfhi(u.z);
        f[6] = bflo(u.w); f[7] = bfhi(u.w);
    } else {
        const float4* q = (const float4*)((const float*)p + idx);
        float4 a = q[0], b = q[1];
        f[0] = a.x; f[1] = a.y; f[2] = a.z; f[3] = a.w;
        f[4] = b.x; f[5] = b.y; f[6] = b.z; f[7] = b.w;
    }
}

// load 2 consecutive elements (idx even)
template<bool BF>
__device__ __forceinline__ void ld2(const void* p, size_t idx, float& a, float& b) {
    if (BF) { u32 w = *(const u32*)((const u16*)p + idx); a = bflo(w); b = bfhi(w); }
    else    { float2 v = *(const float2*)((const float*)p + idx); a = v.x; b = v.y; }
}

__device__ __forceinline__ void fma44(float& acc, const float* f, const float4& a, const float4& b) {
    acc = fmaf(f[0], a.x, acc); acc = fmaf(f[1], a.y, acc);
    acc = fmaf(f[2], a.z, acc); acc = fmaf(f[3], a.w, acc);
    acc = fmaf(f[4], b.x, acc); acc = fmaf(f[5], b.y, acc);
    acc = fmaf(f[6], b.z, acc); acc = fmaf(f[7], b.w, acc);
}

// ---------------- kernel P: dtype probe ----------------
__global__ void k_probe(const u32* __restrict__ xw, int* __restrict__ flag) {
    int cnt = 0;
    #pragma unroll
    for (int i = 0; i < 8; ++i) {
        u32 u = xw[threadIdx.x * 8 + i];
        u32 e = (u >> 7) & 0xffu;           // exponent of low-half-as-bf16
        cnt += (e >= 110 && e <= 140) ? 1 : 0;
    }
    #pragma unroll
    for (int off = 32; off; off >>= 1) cnt += __shfl_xor(cnt, off);
    if (threadIdx.x == 0) flag[0] = (cnt > 256) ? 1 : 0;
}

// ---------------- kernel 0: zero the expert counters ----------------
__global__ void k_init(int* counts) {
    counts[threadIdx.x] = 0;
}

// ---------------- kernel 1: router (dual dtype) ----------------
template<bool BF>
__device__ __forceinline__ void router_body(const void* __restrict__ xg,
                                            const void* __restrict__ wg,
                                            int* __restrict__ counts,
                                            int* __restrict__ topki,
                                            float* __restrict__ topkw,
                                            float* xs, float* svals, int* sidx) {
    const int t = blockIdx.x;
    const int lane = threadIdx.x;

    ld8<BF>(xg, (size_t)t * DIM + lane * 8, &xs[lane * 8]);
    __syncthreads();

    float acc = 0.f;
    for (int k = 0; k < 64; ++k) {
        float f[8]; ld8<BF>(wg, (size_t)lane * DIM + k * 8, f);
        float4 xa = *(const float4*)&xs[k * 8];
        float4 xb = *(const float4*)&xs[k * 8 + 4];
        fma44(acc, f, xa, xb);
    }

    float my = acc;
    for (int s = 0; s < TOPK; ++s) {
        float v = my; int id = lane;
        #pragma unroll
        for (int off = 32; off; off >>= 1) {
            float ov = __shfl_xor(v, off);
            int   oi = __shfl_xor(id, off);
            if (ov > v || (ov == v && oi < id)) { v = ov; id = oi; }
        }
        if (lane == 0) { svals[s] = v; sidx[s] = id; }
        if (lane == id) my = -INFINITY;
    }
    __syncthreads();
    if (lane == 0) {
        float m = svals[0], sum = 0.f, w[TOPK];
        #pragma unroll
        for (int s = 0; s < TOPK; ++s) { w[s] = __expf(svals[s] - m); sum += w[s]; }
        float inv = 1.f / sum;
        #pragma unroll
        for (int s = 0; s < TOPK; ++s) {
            int e = sidx[s];
            topki[t * TOPK + s] = e;
            topkw[t * TOPK + s] = w[s] * inv;
            atomicAdd(&counts[e], 1);
        }
    }
}

__global__ __launch_bounds__(64) void k_router(const void* xg, const void* wg,
                                               const int* __restrict__ flag,
                                               int* counts, int* topki, float* topkw) {
    __shared__ __align__(16) float xs[DIM];
    __shared__ float svals[TOPK];
    __shared__ int sidx[TOPK];
    if (*flag) router_body<true >(xg, wg, counts, topki, topkw, xs, svals, sidx);
    else       router_body<false>(xg, wg, counts, topki, topkw, xs, svals, sidx);
}

// ---------------- kernel 2: prefix sum over 64 experts ----------------
__global__ void k_prefix(const int* __restrict__ counts, int* __restrict__ offsets,
                         int* __restrict__ cursors) {
    if (threadIdx.x == 0) {
        int acc = 0;
        for (int e = 0; e < NEXP; ++e) { offsets[e] = acc; cursors[e] = acc; acc += counts[e]; }
    }
}

// ---------------- kernel 3: scatter tokens into expert buckets ----------------
__global__ void k_scatter(const int* __restrict__ topki, const float* __restrict__ topkw,
                          int* __restrict__ cursors, int* __restrict__ tokl,
                          float* __restrict__ wgtl) {
    int t = blockIdx.x * 256 + threadIdx.x;
    #pragma unroll
    for (int s = 0; s < TOPK; ++s) {
        int e = topki[t * TOPK + s];
        float w = topkw[t * TOPK + s];
        int pos = atomicAdd(&cursors[e], 1);
        tokl[pos] = t;
        wgtl[pos] = w;
    }
}

// ============== fp32 path: split-bf16 MFMA kernels ==============

// ---------------- kernel B: bulk split fp32 tensors -> hi/lo bf16 planes ----------------
// blocks [0,4096) w1 | [4096,8192) w3 | [8192,8448) wsg | [8448,8704) wsu
//        [8704,8960) wsd | [8960,9216) x.  2048 elems per block.
__global__ __launch_bounds__(256) void k_bsplit(
        const float* __restrict__ w1, const float* __restrict__ w3,
        const float* __restrict__ wsg, const float* __restrict__ wsu,
        const float* __restrict__ wsd, const float* __restrict__ x,
        u16* w1h, u16* w1l, u16* w3h, u16* w3l,
        u16* wsgh, u16* wsgl, u16* wsuh, u16* wsul,
        u16* wsdh, u16* wsdl, u16* xh, u16* xl,
        const int* __restrict__ flag) {
    if (*flag) return;
    const int b = blockIdx.x;
    const float* src; u16* dh; u16* dl; size_t base;
    if (b < 4096)      { src = w1;  dh = w1h;  dl = w1l;  base = (size_t)b * 2048; }
    else if (b < 8192) { src = w3;  dh = w3h;  dl = w3l;  base = (size_t)(b - 4096) * 2048; }
    else if (b < 8448) { src = wsg; dh = wsgh; dl = wsgl; base = (size_t)(b - 8192) * 2048; }
    else if (b < 8704) { src = wsu; dh = wsuh; dl = wsul; base = (size_t)(b - 8448) * 2048; }
    else if (b < 8960) { src = wsd; dh = wsdh; dl = wsdl; base = (size_t)(b - 8704) * 2048; }
    else               { src = x;   dh = xh;   dl = xl;   base = (size_t)(b - 8960) * 2048; }
    size_t idx = base + (size_t)threadIdx.x * 8;
    uint4 H, L;
    split8u(src + idx, H, L);
    *(uint4*)(dh + idx) = H;
    *(uint4*)(dl + idx) = L;
}

// ---------------- kernel W: transpose+split w2 [e][i][d] -> hi/lo [e][d][i] ----------------
__global__ __launch_bounds__(256) void k_w2ts(const float* __restrict__ w2,
                                              u16* __restrict__ w2th,
                                              u16* __restrict__ w2tl,
                                              const int* __restrict__ flag) {
    if (*flag) return;
    __shared__ u32 lt[128][65];              // packed hi<<16|lo; pad 65 breaks conflicts
    const int e  = blockIdx.x >> 4;
    const int ic = (blockIdx.x >> 3) & 1;    // i-chunk of 128
    const int dc = blockIdx.x & 7;           // d-chunk of 64
    const int tid = threadIdx.x;
    const float* src = w2 + (size_t)e * INTER * DIM + (size_t)(ic * 128) * DIM + dc * 64;
    #pragma unroll
    for (int p = 0; p < 8; ++p) {
        int f = p * 256 + tid;               // 0..2047 float4s
        int i = f >> 4, dq = f & 15;
        float4 v = *(const float4*)(src + (size_t)i * DIM + dq * 4);
        float vv[4] = {v.x, v.y, v.z, v.w};
        #pragma unroll
        for (int j = 0; j < 4; ++j) {
            u32 u = __float_as_uint(vv[j]);
            u32 hb = u & 0xffff0000u;
            float r = vv[j] - __uint_as_float(hb);
            lt[i][dq * 4 + j] = hb | (__float_as_uint(r) >> 16);
        }
    }
    __syncthreads();
    const int dl = tid & 63, q = tid >> 6;   // wave q handles i-chunk q*32
    size_t rb = ((size_t)e * DIM + dc * 64 + dl) * INTER + ic * 128 + q * 32;
    #pragma unroll
    for (int s = 0; s < 4; ++s) {
        u32 h2[4], l2[4];
        #pragma unroll
        for (int m = 0; m < 4; ++m) {
            u32 p0 = lt[q * 32 + s * 8 + m * 2][dl];
            u32 p1 = lt[q * 32 + s * 8 + m * 2 + 1][dl];
            h2[m] = (p0 >> 16) | (p1 & 0xffff0000u);
            l2[m] = (p0 & 0xffffu) | (p1 << 16);
        }
        uint4 Hv = {h2[0], h2[1], h2[2], h2[3]};
        uint4 Lv = {l2[0], l2[1], l2[2], l2[3]};
        *(uint4*)(w2th + rb + s * 8) = Hv;
        *(uint4*)(w2tl + rb + s * 8) = Lv;
    }
}

// ---------------- kernel SA4: shared up/gate from pre-split planes ----------------
__global__ __launch_bounds__(256) void k_shA4(const u16* __restrict__ xh,
                                              const u16* __restrict__ xl,
                                              const u16* __restrict__ wsgh,
                                              const u16* __restrict__ wsgl,
                                              const u16* __restrict__ wsuh,
                                              const u16* __restrict__ wsul,
                                              u16* __restrict__ vh, u16* __restrict__ vl,
                                              const int* __restrict__ flag) {
    if (*flag) return;
    __shared__ __align__(16) u16 xsh[16 * 512], xsl[16 * 512];   // 32 KB (XOR-swizzled)
    __shared__ __align__(16) u16 vsh[16 * 256], vsl[16 * 256];   // 16 KB
    const int tt = blockIdx.x >> 2;          // token tile (16 rows)
    const int sc = blockIdx.x & 3;           // sinter chunk of 256
    const int tid = threadIdx.x;
    const int w = tid >> 6, lane = tid & 63;
    const int lr = lane & 15, lg = lane >> 4;

    for (int idx = tid; idx < 16 * 64; idx += 256) {
        int r = idx >> 6, c = idx & 63;
        int off = r * 1024 + ((c * 16) ^ ((r & 7) << 4));
        size_t g = (size_t)(tt * 16 + r) * DIM + c * 8;
        *(uint4*)((char*)xsh + off) = *(const uint4*)(xh + g);
        *(uint4*)((char*)xsl + off) = *(const uint4*)(xl + g);
    }
    __syncthreads();

    const f32x4 z4 = {0.f, 0.f, 0.f, 0.f};
    f32x4 ag[4] = {z4, z4, z4, z4};
    f32x4 au[4] = {z4, z4, z4, z4};
    const int j0 = sc * 256 + w * 64;
    for (int ks = 0; ks < 16; ++ks) {
        const int k0 = ks * 32 + lg * 8;
        const int xoff = lr * 1024 + ((k0 * 2) ^ ((lr & 7) << 4));
        bf16x8 ah = *(const bf16x8*)((const char*)xsh + xoff);
        bf16x8 al = *(const bf16x8*)((const char*)xsl + xoff);
        #pragma unroll
        for (int q = 0; q < 4; ++q) {
            const size_t row = (size_t)(j0 + q * 16 + lr) * DIM + k0;
            bf16x8 bh = *(const bf16x8*)(wsgh + row);
            bf16x8 bl = *(const bf16x8*)(wsgl + row);
            ag[q] = mfma16(ah, bh, ag[q]);
            ag[q] = mfma16(ah, bl, ag[q]);
            ag[q] = mfma16(al, bh, ag[q]);
            bh = *(const bf16x8*)(wsuh + row);
            bl = *(const bf16x8*)(wsul + row);
            au[q] = mfma16(ah, bh, au[q]);
            au[q] = mfma16(ah, bl, au[q]);
            au[q] = mfma16(al, bh, au[q]);
        }
    }
    #pragma unroll
    for (int q = 0; q < 4; ++q) {
        #pragma unroll
        for (int r = 0; r < 4; ++r) {
            const int t = lg * 4 + r;
            float g = ag[q][r];
            float v = g / (1.f + __expf(-g)) * au[q][r];
            u16 h16, l16; split1(v, h16, l16);
            const int col = w * 64 + q * 16 + lr;              // 0..255 within chunk
            const int off = t * 512 + ((col * 2) ^ ((t & 7) << 4));
            *(u16*)((char*)vsh + off) = h16;
            *(u16*)((char*)vsl + off) = l16;
        }
    }
    __syncthreads();
    #pragma unroll
    for (int p = 0; p < 2; ++p) {
        int idx = p * 256 + tid;
        int r = idx >> 5, c = idx & 31;
        int off = r * 512 + ((c * 16) ^ ((r & 7) << 4));
        size_t g = (size_t)(tt * 16 + r) * SINTER + sc * 256 + c * 8;
        *(uint4*)(vh + g) = *(const uint4*)((const char*)vsh + off);
        *(uint4*)(vl + g) = *(const uint4*)((const char*)vsl + off);
    }
}

// ---------------- kernel SB4: shared down from pre-split planes ----------------
__global__ __launch_bounds__(256) void k_shB4(const u16* __restrict__ vh,
                                              const u16* __restrict__ vl,
                                              const u16* __restrict__ wsdh,
                                              const u16* __restrict__ wsdl,
                                              float* __restrict__ accum,
                                              const int* __restrict__ flag) {
    if (*flag) return;
    const int tt = blockIdx.x >> 3;          // token tile (16)
    const int dc = blockIdx.x & 7;           // 64-dim chunk
    const int w = threadIdx.x >> 6, lane = threadIdx.x & 63;
    const int lr = lane & 15, lg = lane >> 4;
    const int d0 = dc * 64 + w * 16;
    const u16* vhrow = vh + (size_t)(tt * 16 + lr) * SINTER;
    const u16* vlrow = vl + (size_t)(tt * 16 + lr) * SINTER;
    const u16* whrow = wsdh + (size_t)(d0 + lr) * SINTER;
    const u16* wlrow = wsdl + (size_t)(d0 + lr) * SINTER;
    f32x4 acc = {0.f, 0.f, 0.f, 0.f};
    for (int ks = 0; ks < 32; ++ks) {
        const int k0 = ks * 32 + lg * 8;
        bf16x8 avh = *(const bf16x8*)(vhrow + k0);
        bf16x8 avl = *(const bf16x8*)(vlrow + k0);
        bf16x8 bh  = *(const bf16x8*)(whrow + k0);
        bf16x8 bl  = *(const bf16x8*)(wlrow + k0);
        acc = mfma16(avh, bh, acc);
        acc = mfma16(avh, bl, acc);
        acc = mfma16(avl, bh, acc);
    }
    #pragma unroll
    for (int r = 0; r < 4; ++r)
        accum[(size_t)(tt * 16 + lg * 4 + r) * DIM + d0 + lr] = acc[r];
}

// ---------------- kernel RM4: routed experts from pre-split planes ----------------
__global__ __launch_bounds__(256) void k_routed_mfma4(
        const u16* __restrict__ xh, const u16* __restrict__ xl,
        const u16* __restrict__ w1h, const u16* __restrict__ w1l,
        const u16* __restrict__ w3h, const u16* __restrict__ w3l,
        const u16* __restrict__ w2th, const u16* __restrict__ w2tl,
        const int* __restrict__ flag,
        const int* __restrict__ offsets, const int* __restrict__ counts,
        const int* __restrict__ tokl, const float* __restrict__ wgtl,
        float* __restrict__ accum) {
    if (*flag) return;
    __shared__ __align__(16) u16 xsh[16 * 512], xsl[16 * 512];   // 32 KB
    __shared__ __align__(16) u16 hsh[16 * 256], hsl[16 * 256];   // 16 KB
    __shared__ int   stok[16];
    __shared__ float ssw[16];
    const int e     = blockIdx.x & 63;
    const int slice = blockIdx.x >> 6;       // 0..7
    const int tid  = threadIdx.x;
    const int lane = tid & 63, w = tid >> 6;
    const int lr = lane & 15, lg = lane >> 4;
    const int n = counts[e];
    const int base = offsets[e];
    const size_t wbase  = (size_t)e * INTER * DIM;   // w1/w3 plane expert base
    const size_t w2base = (size_t)e * DIM * INTER;   // w2t plane expert base
    const f32x4 z4 = {0.f, 0.f, 0.f, 0.f};

    for (int tile = slice * 16; tile < n; tile += 128) {
        const int cnt = min(16, n - tile);
        __syncthreads();  // protect stok/ssw/xs/hs from previous iteration
        if (tid < 16) {
            int ok = tid < cnt;
            stok[tid] = ok ? tokl[base + tile + tid] : tokl[base];  // pad: valid token, ssw=0
            ssw[tid]  = ok ? wgtl[base + tile + tid] : 0.f;
        }
        __syncthreads();
        for (int idx = tid; idx < 16 * 64; idx += 256) {
            int r = idx >> 6, c = idx & 63;
            int off = r * 1024 + ((c * 16) ^ ((r & 7) << 4));
            size_t g = (size_t)stok[r] * DIM + c * 8;
            *(uint4*)((char*)xsh + off) = *(const uint4*)(xh + g);
            *(uint4*)((char*)xsl + off) = *(const uint4*)(xl + g);
        }
        __syncthreads();

        // phase 1: H = silu(X W1^T) * (X W3^T) * token_weight ; wave owns inter [w*64,+64)
        f32x4 a1[4] = {z4, z4, z4, z4};
        f32x4 a3[4] = {z4, z4, z4, z4};
        const int j0 = w * 64;
        for (int ks = 0; ks < 16; ++ks) {
            const int k0 = ks * 32 + lg * 8;
            const int xoff = lr * 1024 + ((k0 * 2) ^ ((lr & 7) << 4));
            bf16x8 ah = *(const bf16x8*)((const char*)xsh + xoff);
            bf16x8 al = *(const bf16x8*)((const char*)xsl + xoff);
            #pragma unroll
            for (int q = 0; q < 4; ++q) {
                const size_t row = wbase + (size_t)(j0 + q * 16 + lr) * DIM + k0;
                bf16x8 bh = *(const bf16x8*)(w1h + row);
                bf16x8 bl = *(const bf16x8*)(w1l + row);
                a1[q] = mfma16(ah, bh, a1[q]);
                a1[q] = mfma16(ah, bl, a1[q]);
                a1[q] = mfma16(al, bh, a1[q]);
                bh = *(const bf16x8*)(w3h + row);
                bl = *(const bf16x8*)(w3l + row);
                a3[q] = mfma16(ah, bh, a3[q]);
                a3[q] = mfma16(ah, bl, a3[q]);
                a3[q] = mfma16(al, bh, a3[q]);
            }
        }
        #pragma unroll
        for (int q = 0; q < 4; ++q) {
            #pragma unroll
            for (int r = 0; r < 4; ++r) {
                const int t = lg * 4 + r;
                float g = a1[q][r];
                float h = g / (1.f + __expf(-g)) * a3[q][r] * ssw[t];
                u16 hh16, hl16; split1(h, hh16, hl16);
                const int col = j0 + q * 16 + lr;
                const int off = t * 512 + ((col * 2) ^ ((t & 7) << 4));
                *(u16*)((char*)hsh + off) = hh16;
                *(u16*)((char*)hsl + off) = hl16;
            }
        }
        __syncthreads();

        // phase 2: Y = H @ W2 (via w2t hi/lo planes); wave owns d in [w*128,+128)
        f32x4 ay[8] = {z4, z4, z4, z4, z4, z4, z4, z4};
        for (int ks = 0; ks < 8; ++ks) {
            const int k0 = ks * 32 + lg * 8;
            const int hoff = lr * 512 + ((k0 * 2) ^ ((lr & 7) << 4));
            bf16x8 ah = *(const bf16x8*)((const char*)hsh + hoff);
            bf16x8 al = *(const bf16x8*)((const char*)hsl + hoff);
            #pragma unroll
            for (int q = 0; q < 8; ++q) {
                const size_t row = w2base + (size_t)(w * 128 + q * 16 + lr) * INTER + k0;
                bf16x8 bh = *(const bf16x8*)(w2th + row);
                bf16x8 bl = *(const bf16x8*)(w2tl + row);
                ay[q] = mfma16(ah, bh, ay[q]);
                ay[q] = mfma16(ah, bl, ay[q]);
                ay[q] = mfma16(al, bh, ay[q]);
            }
        }
        #pragma unroll
        for (int q = 0; q < 8; ++q) {
            #pragma unroll
            for (int r = 0; r < 4; ++r) {
                const int t = lg * 4 + r;
                if (t < cnt)
                    atomicAdd(&accum[(size_t)stok[t] * DIM + w * 128 + q * 16 + lr],
                              ay[q][r]);
            }
        }
    }
}

// -------- round-3 on-the-fly-split kernels (fast1 tier: 39 <= ws < 112 MiB) --------

__global__ __launch_bounds__(256) void k_shA3(const float* __restrict__ xg,
                                              const float* __restrict__ wsgf,
                                              const float* __restrict__ wsuf,
                                              u16* __restrict__ vh, u16* __restrict__ vl,
                                              const int* __restrict__ flag) {
    if (*flag) return;
    __shared__ __align__(16) u16 xsh[16 * 512], xsl[16 * 512];
    __shared__ __align__(16) u16 vsh[16 * 256], vsl[16 * 256];
    const int tt = blockIdx.x >> 2;
    const int sc = blockIdx.x & 3;
    const int tid = threadIdx.x;
    const int w = tid >> 6, lane = tid & 63;
    const int lr = lane & 15, lg = lane >> 4;

    for (int idx = tid; idx < 16 * 64; idx += 256) {
        int r = idx >> 6, c = idx & 63;
        int off = r * 1024 + ((c * 16) ^ ((r & 7) << 4));
        uint4 Hq, Lq;
        split8u(xg + (size_t)(tt * 16 + r) * DIM + c * 8, Hq, Lq);
        *(uint4*)((char*)xsh + off) = Hq;
        *(uint4*)((char*)xsl + off) = Lq;
    }
    __syncthreads();

    const f32x4 z4 = {0.f, 0.f, 0.f, 0.f};
    f32x4 ag[4] = {z4, z4, z4, z4};
    f32x4 au[4] = {z4, z4, z4, z4};
    const int j0 = sc * 256 + w * 64;
    for (int ks = 0; ks < 16; ++ks) {
        const int k0 = ks * 32 + lg * 8;
        const int xoff = lr * 1024 + ((k0 * 2) ^ ((lr & 7) << 4));
        bf16x8 ah = *(const bf16x8*)((const char*)xsh + xoff);
        bf16x8 al = *(const bf16x8*)((const char*)xsl + xoff);
        #pragma unroll
        for (int q = 0; q < 4; ++q) {
            const size_t row = (size_t)(j0 + q * 16 + lr) * DIM + k0;
            bf16x8 bh, bl;
            split8(wsgf + row, bh, bl);
            ag[q] = mfma16(ah, bh, ag[q]);
            ag[q] = mfma16(ah, bl, ag[q]);
            ag[q] = mfma16(al, bh, ag[q]);
            split8(wsuf + row, bh, bl);
            au[q] = mfma16(ah, bh, au[q]);
            au[q] = mfma16(ah, bl, au[q]);
            au[q] = mfma16(al, bh, au[q]);
        }
    }
    #pragma unroll
    for (int q = 0; q < 4; ++q) {
        #pragma unroll
        for (int r = 0; r < 4; ++r) {
            const int t = lg * 4 + r;
            float g = ag[q][r];
            float v = g / (1.f + __expf(-g)) * au[q][r];
            u16 h16, l16; split1(v, h16, l16);
            const int col = w * 64 + q * 16 + lr;
            const int off = t * 512 + ((col * 2) ^ ((t & 7) << 4));
            *(u16*)((char*)vsh + off) = h16;
            *(u16*)((char*)vsl + off) = l16;
        }
    }
    __syncthreads();
    #pragma unroll
    for (int p = 0; p < 2; ++p) {
        int idx = p * 256 + tid;
        int r = idx >> 5, c = idx & 31;
        int off = r * 512 + ((c * 16) ^ ((r & 7) << 4));
        size_t g = (size_t)(tt * 16 + r) * SINTER + sc * 256 + c * 8;
        *(uint4*)(vh + g) = *(const uint4*)((const char*)vsh + off);
        *(uint4*)(vl + g) = *(const uint4*)((const char*)vsl + off);
    }
}

__global__ __launch_bounds__(256) void k_shB3(const u16* __restrict__ vh,
                                              const u16* __restrict__ vl,
                                              const float* __restrict__ wsdf,
                                              float* __restrict__ accum,
                                              const int* __restrict__ flag) {
    if (*flag) return;
    const int tt = blockIdx.x >> 3;
    const int dc = blockIdx.x & 7;
    const int w = threadIdx.x >> 6, lane = threadIdx.x & 63;
    const int lr = lane & 15, lg = lane >> 4;
    const int d0 = dc * 64 + w * 16;
    const u16* vhrow = vh + (size_t)(tt * 16 + lr) * SINTER;
    const u16* vlrow = vl + (size_t)(tt * 16 + lr) * SINTER;
    const float* wrow = wsdf + (size_t)(d0 + lr) * SINTER;
    f32x4 acc = {0.f, 0.f, 0.f, 0.f};
    for (int ks = 0; ks < 32; ++ks) {
        const int k0 = ks * 32 + lg * 8;
        bf16x8 avh = *(const bf16x8*)(vhrow + k0);
        bf16x8 avl = *(const bf16x8*)(vlrow + k0);
        bf16x8 bh, bl;
        split8(wrow + k0, bh, bl);
        acc = mfma16(avh, bh, acc);
        acc = mfma16(avh, bl, acc);
        acc = mfma16(avl, bh, acc);
    }
    #pragma unroll
    for (int r = 0; r < 4; ++r)
        accum[(size_t)(tt * 16 + lg * 4 + r) * DIM + d0 + lr] = acc[r];
}

__global__ __launch_bounds__(256) void k_routed_mfma3(
        const float* __restrict__ xg,
        const float* __restrict__ w1f, const float* __restrict__ w3f,
        const u16* __restrict__ w2th, const u16* __restrict__ w2tl,
        const int* __restrict__ flag,
        const int* __restrict__ offsets, const int* __restrict__ counts,
        const int* __restrict__ tokl, const float* __restrict__ wgtl,
        float* __restrict__ accum) {
    if (*flag) return;
    __shared__ __align__(16) u16 xsh[16 * 512], xsl[16 * 512];
    __shared__ __align__(16) u16 hsh[16 * 256], hsl[16 * 256];
    __shared__ int   stok[16];
    __shared__ float ssw[16];
    const int e     = blockIdx.x & 63;
    const int slice = blockIdx.x >> 6;
    const int tid  = threadIdx.x;
    const int lane = tid & 63, w = tid >> 6;
    const int lr = lane & 15, lg = lane >> 4;
    const int n = counts[e];
    const int base = offsets[e];
    const size_t wbase  = (size_t)e * INTER * DIM;
    const size_t w2base = (size_t)e * DIM * INTER;
    const f32x4 z4 = {0.f, 0.f, 0.f, 0.f};

    for (int tile = slice * 16; tile < n; tile += 128) {
        const int cnt = min(16, n - tile);
        __syncthreads();
        if (tid < 16) {
            int ok = tid < cnt;
            stok[tid] = ok ? tokl[base + tile + tid] : tokl[base];
            ssw[tid]  = ok ? wgtl[base + tile + tid] : 0.f;
        }
        __syncthreads();
        for (int idx = tid; idx < 16 * 64; idx += 256) {
            int r = idx >> 6, c = idx & 63;
            int off = r * 1024 + ((c * 16) ^ ((r & 7) << 4));
            uint4 Hq, Lq;
            split8u(xg + (size_t)stok[r] * DIM + c * 8, Hq, Lq);
            *(uint4*)((char*)xsh + off) = Hq;
            *(uint4*)((char*)xsl + off) = Lq;
        }
        __syncthreads();

        f32x4 a1[4] = {z4, z4, z4, z4};
        f32x4 a3[4] = {z4, z4, z4, z4};
        const int j0 = w * 64;
        for (int ks = 0; ks < 16; ++ks) {
            const int k0 = ks * 32 + lg * 8;
            const int xoff = lr * 1024 + ((k0 * 2) ^ ((lr & 7) << 4));
            bf16x8 ah = *(const bf16x8*)((const char*)xsh + xoff);
            bf16x8 al = *(const bf16x8*)((const char*)xsl + xoff);
            #pragma unroll
            for (int q = 0; q < 4; ++q) {
                const size_t row = wbase + (size_t)(j0 + q * 16 + lr) * DIM + k0;
                bf16x8 bh, bl;
                split8(w1f + row, bh, bl);
                a1[q] = mfma16(ah, bh, a1[q]);
                a1[q] = mfma16(ah, bl, a1[q]);
                a1[q] = mfma16(al, bh, a1[q]);
                split8(w3f + row, bh, bl);
                a3[q] = mfma16(ah, bh, a3[q]);
                a3[q] = mfma16(ah, bl, a3[q]);
                a3[q] = mfma16(al, bh, a3[q]);
            }
        }
        #pragma unroll
        for (int q = 0; q < 4; ++q) {
            #pragma unroll
            for (int r = 0; r < 4; ++r) {
                const int t = lg * 4 + r;
                float g = a1[q][r];
                float h = g / (1.f + __expf(-g)) * a3[q][r] * ssw[t];
                u16 hh16, hl16; split1(h, hh16, hl16);
                const int col = j0 + q * 16 + lr;
                const int off = t * 512 + ((col * 2) ^ ((t & 7) << 4));
                *(u16*)((char*)hsh + off) = hh16;
                *(u16*)((char*)hsl + off) = hl16;
            }
        }
        __syncthreads();

        f32x4 ay[8] = {z4, z4, z4, z4, z4, z4, z4, z4};
        for (int ks = 0; ks < 8; ++ks) {
            const int k0 = ks * 32 + lg * 8;
            const int hoff = lr * 512 + ((k0 * 2) ^ ((lr & 7) << 4));
            bf16x8 ah = *(const bf16x8*)((const char*)hsh + hoff);
            bf16x8 al = *(const bf16x8*)((const char*)hsl + hoff);
            #pragma unroll
            for (int q = 0; q < 8; ++q) {
                const size_t row = w2base + (size_t)(w * 128 + q * 16 + lr) * INTER + k0;
                bf16x8 bh = *(const bf16x8*)(w2th + row);
                bf16x8 bl = *(const bf16x8*)(w2tl + row);
                ay[q] = mfma16(ah, bh, ay[q]);
                ay[q] = mfma16(ah, bl, ay[q]);
                ay[q] = mfma16(al, bh, ay[q]);
            }
        }
        #pragma unroll
        for (int q = 0; q < 8; ++q) {
            #pragma unroll
            for (int r = 0; r < 4; ++r) {
                const int t = lg * 4 + r;
                if (t < cnt)
                    atomicAdd(&accum[(size_t)stok[t] * DIM + w * 128 + q * 16 + lr],
                              ay[q][r]);
            }
        }
    }
}

// ============== legacy VALU kernels (bf16 inputs, or tiny-workspace fallback) ==============

template<bool BF>
__device__ __forceinline__ void shared_body(const void* __restrict__ xg,
                                            const void* __restrict__ wsg,
                                            const void* __restrict__ wsu,
                                            const void* __restrict__ wsd,
                                            float* __restrict__ accum,
                                            float* xs /*8*DIM*/, float* vsf /*8*SINTER*/) {
    const int t0 = blockIdx.x * 8;
    const int tid = threadIdx.x;

    for (int idx = tid; idx < 8 * 64; idx += 256) {
        int r = idx >> 6, c = idx & 63;
        ld8<BF>(xg, (size_t)(t0 + r) * DIM + c * 8, &xs[r * DIM + c * 8]);
    }
    __syncthreads();

    for (int jc = 0; jc < 4; ++jc) {
        int j = jc * 256 + tid;
        float ag[8] = {0}, au[8] = {0};
        for (int k = 0; k < 64; ++k) {
            float fg[8], fu[8];
            ld8<BF>(wsg, (size_t)j * DIM + k * 8, fg);
            ld8<BF>(wsu, (size_t)j * DIM + k * 8, fu);
            #pragma unroll
            for (int r = 0; r < 8; ++r) {
                float4 xa = *(const float4*)&xs[r * DIM + k * 8];
                float4 xb = *(const float4*)&xs[r * DIM + k * 8 + 4];
                fma44(ag[r], fg, xa, xb);
                fma44(au[r], fu, xa, xb);
            }
        }
        #pragma unroll
        for (int r = 0; r < 8; ++r) {
            float g = ag[r];
            vsf[r * SINTER + j] = g / (1.f + __expf(-g)) * au[r];
        }
    }
    __syncthreads();

    const int d0 = tid, d1 = tid + 256;
    float aca[8] = {0}, acb[8] = {0};
    for (int k = 0; k < 128; ++k) {
        float fa[8], fb[8];
        ld8<BF>(wsd, (size_t)d0 * SINTER + k * 8, fa);
        ld8<BF>(wsd, (size_t)d1 * SINTER + k * 8, fb);
        #pragma unroll
        for (int r = 0; r < 8; ++r) {
            float4 v0 = *(const float4*)&vsf[r * SINTER + k * 8];
            float4 v1 = *(const float4*)&vsf[r * SINTER + k * 8 + 4];
            fma44(aca[r], fa, v0, v1);
            fma44(acb[r], fb, v0, v1);
        }
    }
    #pragma unroll
    for (int r = 0; r < 8; ++r) {
        accum[(size_t)(t0 + r) * DIM + d0] = aca[r];
        accum[(size_t)(t0 + r) * DIM + d1] = acb[r];
    }
}

__global__ __launch_bounds__(256) void k_shared(const void* xg, const void* wsg,
                                                const void* wsu, const void* wsd,
                                                const int* __restrict__ flag,
                                                float* accum, int bfonly) {
    if (bfonly && !*flag) return;
    __shared__ __align__(16) float xs[8 * DIM];
    __shared__ __align__(16) float vsf[8 * SINTER];
    if (*flag) shared_body<true >(xg, wsg, wsu, wsd, accum, xs, vsf);
    else       shared_body<false>(xg, wsg, wsu, wsd, accum, xs, vsf);
}

template<bool BF>
__device__ __forceinline__ void routed_body(const void* __restrict__ xg,
                                            const void* __restrict__ w1,
                                            const void* __restrict__ w2,
                                            const void* __restrict__ w3,
                                            const int* __restrict__ offsets,
                                            const int* __restrict__ counts,
                                            const int* __restrict__ tokl,
                                            const float* __restrict__ wgtl,
                                            float* __restrict__ accum,
                                            float* xs /*16*DIM*/, float* hsf /*16*INTER*/,
                                            int* stok, float* ssw) {
    const int e = blockIdx.x & 63;
    const int slice = blockIdx.x >> 6;
    const int tid = threadIdx.x;
    const int n = counts[e];
    const int base = offsets[e];
    const size_t wbase = (size_t)e * INTER * DIM;

    for (int tile = slice * 16; tile < n; tile += 64) {
        const int nt = min(16, n - tile);
        __syncthreads();
        if (tid < 16) {
            int ok = tid < nt;
            stok[tid] = ok ? tokl[base + tile + tid] : 0;
            ssw[tid]  = ok ? wgtl[base + tile + tid] : 0.f;
        }
        __syncthreads();
        for (int idx = tid; idx < 16 * 64; idx += 256) {
            int r = idx >> 6, c = idx & 63;
            float* xp = &xs[r * DIM + c * 8];
            if (r < nt) {
                ld8<BF>(xg, (size_t)stok[r] * DIM + c * 8, xp);
            } else {
                #pragma unroll
                for (int q = 0; q < 8; ++q) xp[q] = 0.f;
            }
        }
        __syncthreads();

        {
            float a1[16] = {0}, a3[16] = {0};
            for (int k = 0; k < 64; ++k) {
                float f1[8], f3[8];
                ld8<BF>(w1, wbase + (size_t)tid * DIM + k * 8, f1);
                ld8<BF>(w3, wbase + (size_t)tid * DIM + k * 8, f3);
                #pragma unroll
                for (int t = 0; t < 16; ++t) {
                    float4 xa = *(const float4*)&xs[t * DIM + k * 8];
                    float4 xb = *(const float4*)&xs[t * DIM + k * 8 + 4];
                    fma44(a1[t], f1, xa, xb);
                    fma44(a3[t], f3, xa, xb);
                }
            }
            #pragma unroll
            for (int t = 0; t < 16; ++t) {
                float g = a1[t];
                hsf[t * INTER + tid] = g / (1.f + __expf(-g)) * a3[t] * ssw[t];
            }
        }
        __syncthreads();

        {
            const int d0 = 2 * tid;
            float ay0[16] = {0}, ay1[16] = {0};
            for (int i = 0; i < INTER; i += 4) {
                float b0[4], b1[4];
                #pragma unroll
                for (int ii = 0; ii < 4; ++ii)
                    ld2<BF>(w2, wbase + (size_t)(i + ii) * DIM + d0, b0[ii], b1[ii]);
                #pragma unroll
                for (int t = 0; t < 16; ++t) {
                    float4 h4 = *(const float4*)&hsf[t * INTER + i];
                    ay0[t] = fmaf(h4.x, b0[0], ay0[t]); ay0[t] = fmaf(h4.y, b0[1], ay0[t]);
                    ay0[t] = fmaf(h4.z, b0[2], ay0[t]); ay0[t] = fmaf(h4.w, b0[3], ay0[t]);
                    ay1[t] = fmaf(h4.x, b1[0], ay1[t]); ay1[t] = fmaf(h4.y, b1[1], ay1[t]);
                    ay1[t] = fmaf(h4.z, b1[2], ay1[t]); ay1[t] = fmaf(h4.w, b1[3], ay1[t]);
                }
            }
            for (int t = 0; t < nt; ++t) {
                float* dst = &accum[(size_t)stok[t] * DIM + d0];
                atomicAdd(dst, ay0[t]);
                atomicAdd(dst + 1, ay1[t]);
            }
        }
    }
}

__global__ __launch_bounds__(256) void k_routed(const void* xg, const void* w1,
                                                const void* w2, const void* w3,
                                                const int* __restrict__ flag,
                                                const int* offsets, const int* counts,
                                                const int* tokl, const float* wgtl,
                                                float* accum, int bfonly) {
    if (bfonly && !*flag) return;
    __shared__ __align__(16) float xs[16 * DIM];
    __shared__ __align__(16) float hsf[16 * INTER];
    __shared__ int   stok[16];
    __shared__ float ssw[16];
    if (*flag) routed_body<true >(xg, w1, w2, w3, offsets, counts, tokl, wgtl, accum, xs, hsf, stok, ssw);
    else       routed_body<false>(xg, w1, w2, w3, offsets, counts, tokl, wgtl, accum, xs, hsf, stok, ssw);
}

// ---------------- kernel 6: fp32 accum -> output (dtype per flag) ----------------
__global__ void k_final(const float* __restrict__ accum, void* __restrict__ out,
                        const int* __restrict__ flag) {
    int i = blockIdx.x * 256 + threadIdx.x;
    float2 v = ((const float2*)accum)[i];
    if (*flag) {
        ((u32*)out)[i] = (u32)f2bf(v.x) | ((u32)f2bf(v.y) << 16);
    } else {
        ((float2*)out)[i] = v;
    }
}

extern "C" void kernel_launch(void* const* d_in, const int* in_sizes, int n_in,
                              void* d_out, int out_size, void* d_ws, size_t ws_size,
                              hipStream_t stream) {
    const void* x   = d_in[0];
    const void* wg  = d_in[1];
    const void* w1  = d_in[2];
    const void* w2  = d_in[3];
    const void* w3  = d_in[4];
    const void* wsg = d_in[5];
    const void* wsu = d_in[6];
    const void* wsd = d_in[7];

    char* ws = (char*)d_ws;
    float* accum  = (float*)ws;                              // [0, 2MiB)
    char* ctrl    = ws + ((size_t)2 << 20);
    int* counts   = (int*)ctrl;
    int* offsets  = counts + 64;
    int* cursors  = offsets + 64;
    int* topki    = cursors + 64;                            // 6144 ints
    float* topkw  = (float*)(topki + T_TOK * TOPK);          // 6144 floats
    int* tokl     = (int*)(topkw + T_TOK * TOPK);            // 6144 ints
    float* wgtl   = (float*)(tokl + T_TOK * TOPK);           // 6144 floats
    int* flag     = (int*)(wgtl + T_TOK * TOPK);
    u16* w2th = (u16*)(ws + ((size_t)3   << 20));            // 16 MiB [3,19)
    u16* w2tl = (u16*)(ws + ((size_t)19  << 20));            // 16 MiB [19,35)
    u16* vh   = (u16*)(ws + ((size_t)35  << 20));            //  2 MiB [35,37)
    u16* vl   = (u16*)(ws + ((size_t)37  << 20));            //  2 MiB [37,39)
    u16* w1h  = (u16*)(ws + ((size_t)40  << 20));            // 16 MiB [40,56)
    u16* w1l  = (u16*)(ws + ((size_t)56  << 20));            // 16 MiB [56,72)
    u16* w3h  = (u16*)(ws + ((size_t)72  << 20));            // 16 MiB [72,88)
    u16* w3l  = (u16*)(ws + ((size_t)88  << 20));            // 16 MiB [88,104)
    u16* wsgh = (u16*)(ws + ((size_t)104 << 20));            // 1 MiB each...
    u16* wsgl = (u16*)(ws + ((size_t)105 << 20));
    u16* wsuh = (u16*)(ws + ((size_t)106 << 20));
    u16* wsul = (u16*)(ws + ((size_t)107 << 20));
    u16* wsdh = (u16*)(ws + ((size_t)108 << 20));
    u16* wsdl = (u16*)(ws + ((size_t)109 << 20));
    u16* xh   = (u16*)(ws + ((size_t)110 << 20));
    u16* xl   = (u16*)(ws + ((size_t)111 << 20));
    const bool fast2 = ws_size >= ((size_t)112 << 20);
    const bool fast1 = !fast2 && ws_size >= ((size_t)39 << 20);

    k_probe  <<<1, 64, 0, stream>>>((const u32*)x, flag);
    k_init   <<<1, 64, 0, stream>>>(counts);
    k_router <<<T_TOK, 64, 0, stream>>>(x, wg, flag, counts, topki, topkw);
    k_prefix <<<1, 64, 0, stream>>>(counts, offsets, cursors);
    k_scatter<<<4, 256, 0, stream>>>(topki, topkw, cursors, tokl, wgtl);

    if (fast2) {
        k_bsplit <<<9216, 256, 0, stream>>>((const float*)w1, (const float*)w3,
                                            (const float*)wsg, (const float*)wsu,
                                            (const float*)wsd, (const float*)x,
                                            w1h, w1l, w3h, w3l, wsgh, wsgl, wsuh, wsul,
                                            wsdh, wsdl, xh, xl, flag);
        k_w2ts   <<<1024, 256, 0, stream>>>((const float*)w2, w2th, w2tl, flag);
        k_shA4   <<<256, 256, 0, stream>>>(xh, xl, wsgh, wsgl, wsuh, wsul, vh, vl, flag);
        k_shB4   <<<512, 256, 0, stream>>>(vh, vl, wsdh, wsdl, accum, flag);
        k_routed_mfma4<<<512, 256, 0, stream>>>(xh, xl, w1h, w1l, w3h, w3l,
                                                w2th, w2tl, flag,
                                                offsets, counts, tokl, wgtl, accum);
        // bf16-input fallback (no-ops when flag==0)
        k_shared <<<128, 256, 0, stream>>>(x, wsg, wsu, wsd, flag, accum, 1);
        k_routed <<<256, 256, 0, stream>>>(x, w1, w2, w3, flag, offsets, counts, tokl, wgtl, accum, 1);
    } else if (fast1) {
        k_w2ts   <<<1024, 256, 0, stream>>>((const float*)w2, w2th, w2tl, flag);
        k_shA3   <<<256, 256, 0, stream>>>((const float*)x, (const float*)wsg,
                                           (const float*)wsu, vh, vl, flag);
        k_shB3   <<<512, 256, 0, stream>>>(vh, vl, (const float*)wsd, accum, flag);
        k_routed_mfma3<<<512, 256, 0, stream>>>((const float*)x, (const float*)w1,
                                                (const float*)w3, w2th, w2tl, flag,
                                                offsets, counts, tokl, wgtl, accum);
        k_shared <<<128, 256, 0, stream>>>(x, wsg, wsu, wsd, flag, accum, 1);
        k_routed <<<256, 256, 0, stream>>>(x, w1, w2, w3, flag, offsets, counts, tokl, wgtl, accum, 1);
    } else {
        // tiny workspace: legacy VALU path for both dtypes
        k_shared <<<128, 256, 0, stream>>>(x, wsg, wsu, wsd, flag, accum, 0);
        k_routed <<<256, 256, 0, stream>>>(x, w1, w2, w3, flag, offsets, counts, tokl, wgtl, accum, 0);
    }
    k_final  <<<1024, 256, 0, stream>>>(accum, d_out, flag);
}

// Round 5
// 397.665 us; speedup vs baseline: 1.5244x; 1.1622x over previous
//
#include <hip/hip_runtime.h>
#include <math.h>

// Problem constants
#define T_TOK 1024
#define DIM 512
#define INTER 256
#define SINTER 1024
#define NEXP 64
#define TOPK 6

typedef unsigned short u16;
typedef unsigned int u32;
typedef short bf16x8 __attribute__((ext_vector_type(8)));   // 8 bf16 (4 VGPRs)
typedef float f32x4  __attribute__((ext_vector_type(4)));   // MFMA 16x16 accumulator

__device__ __forceinline__ float bflo(u32 u) { return __uint_as_float(u << 16); }
__device__ __forceinline__ float bfhi(u32 u) { return __uint_as_float(u & 0xffff0000u); }

__device__ __forceinline__ u16 f2bf(float f) {
    u32 u = __float_as_uint(f);
    return (u16)((u + 0x7fffu + ((u >> 16) & 1u)) >> 16);  // RNE
}

__device__ __forceinline__ f32x4 mfma16(bf16x8 a, bf16x8 b, f32x4 c) {
    return __builtin_amdgcn_mfma_f32_16x16x32_bf16(a, b, c, 0, 0, 0);
}

// split fp32 -> (hi bf16, lo bf16): v ~= vh + vl, combined err ~2^-16|v|
__device__ __forceinline__ void split1(float v, u16& h, u16& l) {
    u32 u = __float_as_uint(v);
    u32 hb = u & 0xffff0000u;
    float r = v - __uint_as_float(hb);
    h = (u16)(hb >> 16);
    l = (u16)(__float_as_uint(r) >> 16);
}

// split 8 consecutive fp32 (32B-aligned) into hi/lo bf16x8 packed as uint4
__device__ __forceinline__ void split8u(const float* __restrict__ s, uint4& H, uint4& L) {
    const uint4* q = (const uint4*)s;
    uint4 A = q[0], B = q[1];
    u32 wv[8] = {A.x, A.y, A.z, A.w, B.x, B.y, B.z, B.w};
    u32 hp[4], lp[4];
    #pragma unroll
    for (int i = 0; i < 4; ++i) {
        u32 u0 = wv[2*i], u1 = wv[2*i+1];
        u32 h0 = u0 & 0xffff0000u, h1 = u1 & 0xffff0000u;
        float r0 = __uint_as_float(u0) - __uint_as_float(h0);
        float r1 = __uint_as_float(u1) - __uint_as_float(h1);
        hp[i] = (h0 >> 16) | h1;
        lp[i] = (__float_as_uint(r0) >> 16) | (__float_as_uint(r1) & 0xffff0000u);
    }
    H.x = hp[0]; H.y = hp[1]; H.z = hp[2]; H.w = hp[3];
    L.x = lp[0]; L.y = lp[1]; L.z = lp[2]; L.w = lp[3];
}

__device__ __forceinline__ void split8(const float* __restrict__ s, bf16x8& h, bf16x8& l) {
    uint4 H, L;
    split8u(s, H, L);
    h = *(bf16x8*)&H;
    l = *(bf16x8*)&L;
}

// load 8 consecutive elements (idx must be a multiple of 8) as floats
template<bool BF>
__device__ __forceinline__ void ld8(const void* p, size_t idx, float* f) {
    if (BF) {
        uint4 u = *(const uint4*)((const u16*)p + idx);
        f[0] = bflo(u.x); f[1] = bfhi(u.x);
        f[2] = bflo(u.y); f[3] = bfhi(u.y);
        f[4] = bflo(u.z); f[5] = bfhi(u.z);
        f[6] = bflo(u.w); f[7] = bfhi(u.w);
    } else {
        const float4* q = (const float4*)((const float*)p + idx);
        float4 a = q[0], b = q[1];
        f[0] = a.x; f[1] = a.y; f[2] = a.z; f[3] = a.w;
        f[4] = b.x; f[5] = b.y; f[6] = b.z; f[7] = b.w;
    }
}

// load 2 consecutive elements (idx even)
template<bool BF>
__device__ __forceinline__ void ld2(const void* p, size_t idx, float& a, float& b) {
    if (BF) { u32 w = *(const u32*)((const u16*)p + idx); a = bflo(w); b = bfhi(w); }
    else    { float2 v = *(const float2*)((const float*)p + idx); a = v.x; b = v.y; }
}

__device__ __forceinline__ void fma44(float& acc, const float* f, const float4& a, const float4& b) {
    acc = fmaf(f[0], a.x, acc); acc = fmaf(f[1], a.y, acc);
    acc = fmaf(f[2], a.z, acc); acc = fmaf(f[3], a.w, acc);
    acc = fmaf(f[4], b.x, acc); acc = fmaf(f[5], b.y, acc);
    acc = fmaf(f[6], b.z, acc); acc = fmaf(f[7], b.w, acc);
}

// ---------------- kernel P: dtype probe ----------------
__global__ void k_probe(const u32* __restrict__ xw, int* __restrict__ flag) {
    int cnt = 0;
    #pragma unroll
    for (int i = 0; i < 8; ++i) {
        u32 u = xw[threadIdx.x * 8 + i];
        u32 e = (u >> 7) & 0xffu;           // exponent of low-half-as-bf16
        cnt += (e >= 110 && e <= 140) ? 1 : 0;
    }
    #pragma unroll
    for (int off = 32; off; off >>= 1) cnt += __shfl_xor(cnt, off);
    if (threadIdx.x == 0) flag[0] = (cnt > 256) ? 1 : 0;
}

// ---------------- kernel 0: zero the expert counters ----------------
__global__ void k_init(int* counts) {
    counts[threadIdx.x] = 0;
}

// ---------------- kernel 1: router (dual dtype) ----------------
template<bool BF>
__device__ __forceinline__ void router_body(const void* __restrict__ xg,
                                            const void* __restrict__ wg,
                                            int* __restrict__ counts,
                                            int* __restrict__ topki,
                                            float* __restrict__ topkw,
                                            float* xs, float* svals, int* sidx) {
    const int t = blockIdx.x;
    const int lane = threadIdx.x;

    ld8<BF>(xg, (size_t)t * DIM + lane * 8, &xs[lane * 8]);
    __syncthreads();

    float acc = 0.f;
    for (int k = 0; k < 64; ++k) {
        float f[8]; ld8<BF>(wg, (size_t)lane * DIM + k * 8, f);
        float4 xa = *(const float4*)&xs[k * 8];
        float4 xb = *(const float4*)&xs[k * 8 + 4];
        fma44(acc, f, xa, xb);
    }

    float my = acc;
    for (int s = 0; s < TOPK; ++s) {
        float v = my; int id = lane;
        #pragma unroll
        for (int off = 32; off; off >>= 1) {
            float ov = __shfl_xor(v, off);
            int   oi = __shfl_xor(id, off);
            if (ov > v || (ov == v && oi < id)) { v = ov; id = oi; }
        }
        if (lane == 0) { svals[s] = v; sidx[s] = id; }
        if (lane == id) my = -INFINITY;
    }
    __syncthreads();
    if (lane == 0) {
        float m = svals[0], sum = 0.f, w[TOPK];
        #pragma unroll
        for (int s = 0; s < TOPK; ++s) { w[s] = __expf(svals[s] - m); sum += w[s]; }
        float inv = 1.f / sum;
        #pragma unroll
        for (int s = 0; s < TOPK; ++s) {
            int e = sidx[s];
            topki[t * TOPK + s] = e;
            topkw[t * TOPK + s] = w[s] * inv;
            atomicAdd(&counts[e], 1);
        }
    }
}

__global__ __launch_bounds__(64) void k_router(const void* xg, const void* wg,
                                               const int* __restrict__ flag,
                                               int* counts, int* topki, float* topkw) {
    __shared__ __align__(16) float xs[DIM];
    __shared__ float svals[TOPK];
    __shared__ int sidx[TOPK];
    if (*flag) router_body<true >(xg, wg, counts, topki, topkw, xs, svals, sidx);
    else       router_body<false>(xg, wg, counts, topki, topkw, xs, svals, sidx);
}

// ---------------- kernel 2: prefix sum over 64 experts ----------------
__global__ void k_prefix(const int* __restrict__ counts, int* __restrict__ offsets,
                         int* __restrict__ cursors) {
    if (threadIdx.x == 0) {
        int acc = 0;
        for (int e = 0; e < NEXP; ++e) { offsets[e] = acc; cursors[e] = acc; acc += counts[e]; }
    }
}

// ---------------- kernel 3: scatter tokens into expert buckets ----------------
__global__ void k_scatter(const int* __restrict__ topki, const float* __restrict__ topkw,
                          int* __restrict__ cursors, int* __restrict__ tokl,
                          float* __restrict__ wgtl) {
    int t = blockIdx.x * 256 + threadIdx.x;
    #pragma unroll
    for (int s = 0; s < TOPK; ++s) {
        int e = topki[t * TOPK + s];
        float w = topkw[t * TOPK + s];
        int pos = atomicAdd(&cursors[e], 1);
        tokl[pos] = t;
        wgtl[pos] = w;
    }
}

// ============== fp32 path: split-bf16 MFMA kernels ==============

// ---------------- kernel B: bulk split fp32 tensors -> hi/lo bf16 planes ----------------
__global__ __launch_bounds__(256) void k_bsplit(
        const float* __restrict__ w1, const float* __restrict__ w3,
        const float* __restrict__ wsg, const float* __restrict__ wsu,
        const float* __restrict__ wsd, const float* __restrict__ x,
        u16* w1h, u16* w1l, u16* w3h, u16* w3l,
        u16* wsgh, u16* wsgl, u16* wsuh, u16* wsul,
        u16* wsdh, u16* wsdl, u16* xh, u16* xl,
        const int* __restrict__ flag) {
    if (*flag) return;
    const int b = blockIdx.x;
    const float* src; u16* dh; u16* dl; size_t base;
    if (b < 4096)      { src = w1;  dh = w1h;  dl = w1l;  base = (size_t)b * 2048; }
    else if (b < 8192) { src = w3;  dh = w3h;  dl = w3l;  base = (size_t)(b - 4096) * 2048; }
    else if (b < 8448) { src = wsg; dh = wsgh; dl = wsgl; base = (size_t)(b - 8192) * 2048; }
    else if (b < 8704) { src = wsu; dh = wsuh; dl = wsul; base = (size_t)(b - 8448) * 2048; }
    else if (b < 8960) { src = wsd; dh = wsdh; dl = wsdl; base = (size_t)(b - 8704) * 2048; }
    else               { src = x;   dh = xh;   dl = xl;   base = (size_t)(b - 8960) * 2048; }
    size_t idx = base + (size_t)threadIdx.x * 8;
    uint4 H, L;
    split8u(src + idx, H, L);
    *(uint4*)(dh + idx) = H;
    *(uint4*)(dl + idx) = L;
}

// ---------------- kernel W: transpose+split w2 [e][i][d] -> hi/lo [e][d][i] ----------------
__global__ __launch_bounds__(256) void k_w2ts(const float* __restrict__ w2,
                                              u16* __restrict__ w2th,
                                              u16* __restrict__ w2tl,
                                              const int* __restrict__ flag) {
    if (*flag) return;
    __shared__ u32 lt[128][65];              // packed hi<<16|lo; pad 65 breaks conflicts
    const int e  = blockIdx.x >> 4;
    const int ic = (blockIdx.x >> 3) & 1;    // i-chunk of 128
    const int dc = blockIdx.x & 7;           // d-chunk of 64
    const int tid = threadIdx.x;
    const float* src = w2 + (size_t)e * INTER * DIM + (size_t)(ic * 128) * DIM + dc * 64;
    #pragma unroll
    for (int p = 0; p < 8; ++p) {
        int f = p * 256 + tid;               // 0..2047 float4s
        int i = f >> 4, dq = f & 15;
        float4 v = *(const float4*)(src + (size_t)i * DIM + dq * 4);
        float vv[4] = {v.x, v.y, v.z, v.w};
        #pragma unroll
        for (int j = 0; j < 4; ++j) {
            u32 u = __float_as_uint(vv[j]);
            u32 hb = u & 0xffff0000u;
            float r = vv[j] - __uint_as_float(hb);
            lt[i][dq * 4 + j] = hb | (__float_as_uint(r) >> 16);
        }
    }
    __syncthreads();
    const int dl = tid & 63, q = tid >> 6;   // wave q handles i-chunk q*32
    size_t rb = ((size_t)e * DIM + dc * 64 + dl) * INTER + ic * 128 + q * 32;
    #pragma unroll
    for (int s = 0; s < 4; ++s) {
        u32 h2[4], l2[4];
        #pragma unroll
        for (int m = 0; m < 4; ++m) {
            u32 p0 = lt[q * 32 + s * 8 + m * 2][dl];
            u32 p1 = lt[q * 32 + s * 8 + m * 2 + 1][dl];
            h2[m] = (p0 >> 16) | (p1 & 0xffff0000u);
            l2[m] = (p0 & 0xffffu) | (p1 << 16);
        }
        uint4 Hv = {h2[0], h2[1], h2[2], h2[3]};
        uint4 Lv = {l2[0], l2[1], l2[2], l2[3]};
        *(uint4*)(w2th + rb + s * 8) = Hv;
        *(uint4*)(w2tl + rb + s * 8) = Lv;
    }
}

// ---------------- kernel SA4: shared up/gate from pre-split planes ----------------
__global__ __launch_bounds__(256) void k_shA4(const u16* __restrict__ xh,
                                              const u16* __restrict__ xl,
                                              const u16* __restrict__ wsgh,
                                              const u16* __restrict__ wsgl,
                                              const u16* __restrict__ wsuh,
                                              const u16* __restrict__ wsul,
                                              u16* __restrict__ vh, u16* __restrict__ vl,
                                              const int* __restrict__ flag) {
    if (*flag) return;
    __shared__ __align__(16) u16 xsh[16 * 512], xsl[16 * 512];   // 32 KB (XOR-swizzled)
    __shared__ __align__(16) u16 vsh[16 * 256], vsl[16 * 256];   // 16 KB
    const int tt = blockIdx.x >> 2;          // token tile (16 rows)
    const int sc = blockIdx.x & 3;           // sinter chunk of 256
    const int tid = threadIdx.x;
    const int w = tid >> 6, lane = tid & 63;
    const int lr = lane & 15, lg = lane >> 4;

    for (int idx = tid; idx < 16 * 64; idx += 256) {
        int r = idx >> 6, c = idx & 63;
        int off = r * 1024 + ((c * 16) ^ ((r & 7) << 4));
        size_t g = (size_t)(tt * 16 + r) * DIM + c * 8;
        *(uint4*)((char*)xsh + off) = *(const uint4*)(xh + g);
        *(uint4*)((char*)xsl + off) = *(const uint4*)(xl + g);
    }
    __syncthreads();

    const f32x4 z4 = {0.f, 0.f, 0.f, 0.f};
    f32x4 ag[4] = {z4, z4, z4, z4};
    f32x4 au[4] = {z4, z4, z4, z4};
    const int j0 = sc * 256 + w * 64;
    #pragma unroll 1
    for (int ks = 0; ks < 16; ++ks) {        // unroll 1: full unroll spills to scratch (r4 post-mortem)
        const int k0 = ks * 32 + lg * 8;
        const int xoff = lr * 1024 + ((k0 * 2) ^ ((lr & 7) << 4));
        bf16x8 ah = *(const bf16x8*)((const char*)xsh + xoff);
        bf16x8 al = *(const bf16x8*)((const char*)xsl + xoff);
        #pragma unroll
        for (int q = 0; q < 4; ++q) {
            const size_t row = (size_t)(j0 + q * 16 + lr) * DIM + k0;
            bf16x8 bh = *(const bf16x8*)(wsgh + row);
            bf16x8 bl = *(const bf16x8*)(wsgl + row);
            ag[q] = mfma16(ah, bh, ag[q]);
            ag[q] = mfma16(ah, bl, ag[q]);
            ag[q] = mfma16(al, bh, ag[q]);
            bh = *(const bf16x8*)(wsuh + row);
            bl = *(const bf16x8*)(wsul + row);
            au[q] = mfma16(ah, bh, au[q]);
            au[q] = mfma16(ah, bl, au[q]);
            au[q] = mfma16(al, bh, au[q]);
        }
    }
    #pragma unroll
    for (int q = 0; q < 4; ++q) {
        #pragma unroll
        for (int r = 0; r < 4; ++r) {
            const int t = lg * 4 + r;
            float g = ag[q][r];
            float v = g / (1.f + __expf(-g)) * au[q][r];
            u16 h16, l16; split1(v, h16, l16);
            const int col = w * 64 + q * 16 + lr;              // 0..255 within chunk
            const int off = t * 512 + ((col * 2) ^ ((t & 7) << 4));
            *(u16*)((char*)vsh + off) = h16;
            *(u16*)((char*)vsl + off) = l16;
        }
    }
    __syncthreads();
    #pragma unroll
    for (int p = 0; p < 2; ++p) {
        int idx = p * 256 + tid;
        int r = idx >> 5, c = idx & 31;
        int off = r * 512 + ((c * 16) ^ ((r & 7) << 4));
        size_t g = (size_t)(tt * 16 + r) * SINTER + sc * 256 + c * 8;
        *(uint4*)(vh + g) = *(const uint4*)((const char*)vsh + off);
        *(uint4*)(vl + g) = *(const uint4*)((const char*)vsl + off);
    }
}

// ---------------- kernel SB4: shared down from pre-split planes ----------------
__global__ __launch_bounds__(256) void k_shB4(const u16* __restrict__ vh,
                                              const u16* __restrict__ vl,
                                              const u16* __restrict__ wsdh,
                                              const u16* __restrict__ wsdl,
                                              float* __restrict__ accum,
                                              const int* __restrict__ flag) {
    if (*flag) return;
    const int tt = blockIdx.x >> 3;          // token tile (16)
    const int dc = blockIdx.x & 7;           // 64-dim chunk
    const int w = threadIdx.x >> 6, lane = threadIdx.x & 63;
    const int lr = lane & 15, lg = lane >> 4;
    const int d0 = dc * 64 + w * 16;
    const u16* vhrow = vh + (size_t)(tt * 16 + lr) * SINTER;
    const u16* vlrow = vl + (size_t)(tt * 16 + lr) * SINTER;
    const u16* whrow = wsdh + (size_t)(d0 + lr) * SINTER;
    const u16* wlrow = wsdl + (size_t)(d0 + lr) * SINTER;
    f32x4 acc = {0.f, 0.f, 0.f, 0.f};
    #pragma unroll 4
    for (int ks = 0; ks < 32; ++ks) {        // unroll 4: bounded in-flight loads, no spill
        const int k0 = ks * 32 + lg * 8;
        bf16x8 avh = *(const bf16x8*)(vhrow + k0);
        bf16x8 avl = *(const bf16x8*)(vlrow + k0);
        bf16x8 bh  = *(const bf16x8*)(whrow + k0);
        bf16x8 bl  = *(const bf16x8*)(wlrow + k0);
        acc = mfma16(avh, bh, acc);
        acc = mfma16(avh, bl, acc);
        acc = mfma16(avl, bh, acc);
    }
    #pragma unroll
    for (int r = 0; r < 4; ++r)
        accum[(size_t)(tt * 16 + lg * 4 + r) * DIM + d0 + lr] = acc[r];
}

// ---------------- kernel RM4: routed experts from pre-split planes ----------------
__global__ __launch_bounds__(256) void k_routed_mfma4(
        const u16* __restrict__ xh, const u16* __restrict__ xl,
        const u16* __restrict__ w1h, const u16* __restrict__ w1l,
        const u16* __restrict__ w3h, const u16* __restrict__ w3l,
        const u16* __restrict__ w2th, const u16* __restrict__ w2tl,
        const int* __restrict__ flag,
        const int* __restrict__ offsets, const int* __restrict__ counts,
        const int* __restrict__ tokl, const float* __restrict__ wgtl,
        float* __restrict__ accum) {
    if (*flag) return;
    __shared__ __align__(16) u16 xsh[16 * 512], xsl[16 * 512];   // 32 KB
    __shared__ __align__(16) u16 hsh[16 * 256], hsl[16 * 256];   // 16 KB
    __shared__ int   stok[16];
    __shared__ float ssw[16];
    const int e     = blockIdx.x & 63;
    const int slice = blockIdx.x >> 6;       // 0..7
    const int tid  = threadIdx.x;
    const int lane = tid & 63, w = tid >> 6;
    const int lr = lane & 15, lg = lane >> 4;
    const int n = counts[e];
    const int base = offsets[e];
    const size_t wbase  = (size_t)e * INTER * DIM;   // w1/w3 plane expert base
    const size_t w2base = (size_t)e * DIM * INTER;   // w2t plane expert base
    const f32x4 z4 = {0.f, 0.f, 0.f, 0.f};

    for (int tile = slice * 16; tile < n; tile += 128) {
        const int cnt = min(16, n - tile);
        __syncthreads();  // protect stok/ssw/xs/hs from previous iteration
        if (tid < 16) {
            int ok = tid < cnt;
            stok[tid] = ok ? tokl[base + tile + tid] : tokl[base];  // pad: valid token, ssw=0
            ssw[tid]  = ok ? wgtl[base + tile + tid] : 0.f;
        }
        __syncthreads();
        for (int idx = tid; idx < 16 * 64; idx += 256) {
            int r = idx >> 6, c = idx & 63;
            int off = r * 1024 + ((c * 16) ^ ((r & 7) << 4));
            size_t g = (size_t)stok[r] * DIM + c * 8;
            *(uint4*)((char*)xsh + off) = *(const uint4*)(xh + g);
            *(uint4*)((char*)xsl + off) = *(const uint4*)(xl + g);
        }
        __syncthreads();

        // phase 1: H = silu(X W1^T) * (X W3^T) * token_weight ; wave owns inter [w*64,+64)
        f32x4 a1[4] = {z4, z4, z4, z4};
        f32x4 a3[4] = {z4, z4, z4, z4};
        const int j0 = w * 64;
        #pragma unroll 1
        for (int ks = 0; ks < 16; ++ks) {    // unroll 1: full unroll spills to scratch (r4 post-mortem)
            const int k0 = ks * 32 + lg * 8;
            const int xoff = lr * 1024 + ((k0 * 2) ^ ((lr & 7) << 4));
            bf16x8 ah = *(const bf16x8*)((const char*)xsh + xoff);
            bf16x8 al = *(const bf16x8*)((const char*)xsl + xoff);
            #pragma unroll
            for (int q = 0; q < 4; ++q) {
                const size_t row = wbase + (size_t)(j0 + q * 16 + lr) * DIM + k0;
                bf16x8 bh = *(const bf16x8*)(w1h + row);
                bf16x8 bl = *(const bf16x8*)(w1l + row);
                a1[q] = mfma16(ah, bh, a1[q]);
                a1[q] = mfma16(ah, bl, a1[q]);
                a1[q] = mfma16(al, bh, a1[q]);
                bh = *(const bf16x8*)(w3h + row);
                bl = *(const bf16x8*)(w3l + row);
                a3[q] = mfma16(ah, bh, a3[q]);
                a3[q] = mfma16(ah, bl, a3[q]);
                a3[q] = mfma16(al, bh, a3[q]);
            }
        }
        #pragma unroll
        for (int q = 0; q < 4; ++q) {
            #pragma unroll
            for (int r = 0; r < 4; ++r) {
                const int t = lg * 4 + r;
                float g = a1[q][r];
                float h = g / (1.f + __expf(-g)) * a3[q][r] * ssw[t];
                u16 hh16, hl16; split1(h, hh16, hl16);
                const int col = j0 + q * 16 + lr;
                const int off = t * 512 + ((col * 2) ^ ((t & 7) << 4));
                *(u16*)((char*)hsh + off) = hh16;
                *(u16*)((char*)hsl + off) = hl16;
            }
        }
        __syncthreads();

        // phase 2: Y = H @ W2 (via w2t hi/lo planes); wave owns d in [w*128,+128)
        f32x4 ay[8] = {z4, z4, z4, z4, z4, z4, z4, z4};
        #pragma unroll 1
        for (int ks = 0; ks < 8; ++ks) {     // unroll 1: see above
            const int k0 = ks * 32 + lg * 8;
            const int hoff = lr * 512 + ((k0 * 2) ^ ((lr & 7) << 4));
            bf16x8 ah = *(const bf16x8*)((const char*)hsh + hoff);
            bf16x8 al = *(const bf16x8*)((const char*)hsl + hoff);
            #pragma unroll
            for (int q = 0; q < 8; ++q) {
                const size_t row = w2base + (size_t)(w * 128 + q * 16 + lr) * INTER + k0;
                bf16x8 bh = *(const bf16x8*)(w2th + row);
                bf16x8 bl = *(const bf16x8*)(w2tl + row);
                ay[q] = mfma16(ah, bh, ay[q]);
                ay[q] = mfma16(ah, bl, ay[q]);
                ay[q] = mfma16(al, bh, ay[q]);
            }
        }
        #pragma unroll
        for (int q = 0; q < 8; ++q) {
            #pragma unroll
            for (int r = 0; r < 4; ++r) {
                const int t = lg * 4 + r;
                if (t < cnt)
                    atomicAdd(&accum[(size_t)stok[t] * DIM + w * 128 + q * 16 + lr],
                              ay[q][r]);
            }
        }
    }
}

// -------- round-3 on-the-fly-split kernels (fast1 tier: 39 <= ws < 112 MiB) --------

__global__ __launch_bounds__(256) void k_shA3(const float* __restrict__ xg,
                                              const float* __restrict__ wsgf,
                                              const float* __restrict__ wsuf,
                                              u16* __restrict__ vh, u16* __restrict__ vl,
                                              const int* __restrict__ flag) {
    if (*flag) return;
    __shared__ __align__(16) u16 xsh[16 * 512], xsl[16 * 512];
    __shared__ __align__(16) u16 vsh[16 * 256], vsl[16 * 256];
    const int tt = blockIdx.x >> 2;
    const int sc = blockIdx.x & 3;
    const int tid = threadIdx.x;
    const int w = tid >> 6, lane = tid & 63;
    const int lr = lane & 15, lg = lane >> 4;

    for (int idx = tid; idx < 16 * 64; idx += 256) {
        int r = idx >> 6, c = idx & 63;
        int off = r * 1024 + ((c * 16) ^ ((r & 7) << 4));
        uint4 Hq, Lq;
        split8u(xg + (size_t)(tt * 16 + r) * DIM + c * 8, Hq, Lq);
        *(uint4*)((char*)xsh + off) = Hq;
        *(uint4*)((char*)xsl + off) = Lq;
    }
    __syncthreads();

    const f32x4 z4 = {0.f, 0.f, 0.f, 0.f};
    f32x4 ag[4] = {z4, z4, z4, z4};
    f32x4 au[4] = {z4, z4, z4, z4};
    const int j0 = sc * 256 + w * 64;
    #pragma unroll 1
    for (int ks = 0; ks < 16; ++ks) {
        const int k0 = ks * 32 + lg * 8;
        const int xoff = lr * 1024 + ((k0 * 2) ^ ((lr & 7) << 4));
        bf16x8 ah = *(const bf16x8*)((const char*)xsh + xoff);
        bf16x8 al = *(const bf16x8*)((const char*)xsl + xoff);
        #pragma unroll
        for (int q = 0; q < 4; ++q) {
            const size_t row = (size_t)(j0 + q * 16 + lr) * DIM + k0;
            bf16x8 bh, bl;
            split8(wsgf + row, bh, bl);
            ag[q] = mfma16(ah, bh, ag[q]);
            ag[q] = mfma16(ah, bl, ag[q]);
            ag[q] = mfma16(al, bh, ag[q]);
            split8(wsuf + row, bh, bl);
            au[q] = mfma16(ah, bh, au[q]);
            au[q] = mfma16(ah, bl, au[q]);
            au[q] = mfma16(al, bh, au[q]);
        }
    }
    #pragma unroll
    for (int q = 0; q < 4; ++q) {
        #pragma unroll
        for (int r = 0; r < 4; ++r) {
            const int t = lg * 4 + r;
            float g = ag[q][r];
            float v = g / (1.f + __expf(-g)) * au[q][r];
            u16 h16, l16; split1(v, h16, l16);
            const int col = w * 64 + q * 16 + lr;
            const int off = t * 512 + ((col * 2) ^ ((t & 7) << 4));
            *(u16*)((char*)vsh + off) = h16;
            *(u16*)((char*)vsl + off) = l16;
        }
    }
    __syncthreads();
    #pragma unroll
    for (int p = 0; p < 2; ++p) {
        int idx = p * 256 + tid;
        int r = idx >> 5, c = idx & 31;
        int off = r * 512 + ((c * 16) ^ ((r & 7) << 4));
        size_t g = (size_t)(tt * 16 + r) * SINTER + sc * 256 + c * 8;
        *(uint4*)(vh + g) = *(const uint4*)((const char*)vsh + off);
        *(uint4*)(vl + g) = *(const uint4*)((const char*)vsl + off);
    }
}

__global__ __launch_bounds__(256) void k_shB3(const u16* __restrict__ vh,
                                              const u16* __restrict__ vl,
                                              const float* __restrict__ wsdf,
                                              float* __restrict__ accum,
                                              const int* __restrict__ flag) {
    if (*flag) return;
    const int tt = blockIdx.x >> 3;
    const int dc = blockIdx.x & 7;
    const int w = threadIdx.x >> 6, lane = threadIdx.x & 63;
    const int lr = lane & 15, lg = lane >> 4;
    const int d0 = dc * 64 + w * 16;
    const u16* vhrow = vh + (size_t)(tt * 16 + lr) * SINTER;
    const u16* vlrow = vl + (size_t)(tt * 16 + lr) * SINTER;
    const float* wrow = wsdf + (size_t)(d0 + lr) * SINTER;
    f32x4 acc = {0.f, 0.f, 0.f, 0.f};
    #pragma unroll 2
    for (int ks = 0; ks < 32; ++ks) {
        const int k0 = ks * 32 + lg * 8;
        bf16x8 avh = *(const bf16x8*)(vhrow + k0);
        bf16x8 avl = *(const bf16x8*)(vlrow + k0);
        bf16x8 bh, bl;
        split8(wrow + k0, bh, bl);
        acc = mfma16(avh, bh, acc);
        acc = mfma16(avh, bl, acc);
        acc = mfma16(avl, bh, acc);
    }
    #pragma unroll
    for (int r = 0; r < 4; ++r)
        accum[(size_t)(tt * 16 + lg * 4 + r) * DIM + d0 + lr] = acc[r];
}

__global__ __launch_bounds__(256) void k_routed_mfma3(
        const float* __restrict__ xg,
        const float* __restrict__ w1f, const float* __restrict__ w3f,
        const u16* __restrict__ w2th, const u16* __restrict__ w2tl,
        const int* __restrict__ flag,
        const int* __restrict__ offsets, const int* __restrict__ counts,
        const int* __restrict__ tokl, const float* __restrict__ wgtl,
        float* __restrict__ accum) {
    if (*flag) return;
    __shared__ __align__(16) u16 xsh[16 * 512], xsl[16 * 512];
    __shared__ __align__(16) u16 hsh[16 * 256], hsl[16 * 256];
    __shared__ int   stok[16];
    __shared__ float ssw[16];
    const int e     = blockIdx.x & 63;
    const int slice = blockIdx.x >> 6;
    const int tid  = threadIdx.x;
    const int lane = tid & 63, w = tid >> 6;
    const int lr = lane & 15, lg = lane >> 4;
    const int n = counts[e];
    const int base = offsets[e];
    const size_t wbase  = (size_t)e * INTER * DIM;
    const size_t w2base = (size_t)e * DIM * INTER;
    const f32x4 z4 = {0.f, 0.f, 0.f, 0.f};

    for (int tile = slice * 16; tile < n; tile += 128) {
        const int cnt = min(16, n - tile);
        __syncthreads();
        if (tid < 16) {
            int ok = tid < cnt;
            stok[tid] = ok ? tokl[base + tile + tid] : tokl[base];
            ssw[tid]  = ok ? wgtl[base + tile + tid] : 0.f;
        }
        __syncthreads();
        for (int idx = tid; idx < 16 * 64; idx += 256) {
            int r = idx >> 6, c = idx & 63;
            int off = r * 1024 + ((c * 16) ^ ((r & 7) << 4));
            uint4 Hq, Lq;
            split8u(xg + (size_t)stok[r] * DIM + c * 8, Hq, Lq);
            *(uint4*)((char*)xsh + off) = Hq;
            *(uint4*)((char*)xsl + off) = Lq;
        }
        __syncthreads();

        f32x4 a1[4] = {z4, z4, z4, z4};
        f32x4 a3[4] = {z4, z4, z4, z4};
        const int j0 = w * 64;
        #pragma unroll 1
        for (int ks = 0; ks < 16; ++ks) {
            const int k0 = ks * 32 + lg * 8;
            const int xoff = lr * 1024 + ((k0 * 2) ^ ((lr & 7) << 4));
            bf16x8 ah = *(const bf16x8*)((const char*)xsh + xoff);
            bf16x8 al = *(const bf16x8*)((const char*)xsl + xoff);
            #pragma unroll
            for (int q = 0; q < 4; ++q) {
                const size_t row = wbase + (size_t)(j0 + q * 16 + lr) * DIM + k0;
                bf16x8 bh, bl;
                split8(w1f + row, bh, bl);
                a1[q] = mfma16(ah, bh, a1[q]);
                a1[q] = mfma16(ah, bl, a1[q]);
                a1[q] = mfma16(al, bh, a1[q]);
                split8(w3f + row, bh, bl);
                a3[q] = mfma16(ah, bh, a3[q]);
                a3[q] = mfma16(ah, bl, a3[q]);
                a3[q] = mfma16(al, bh, a3[q]);
            }
        }
        #pragma unroll
        for (int q = 0; q < 4; ++q) {
            #pragma unroll
            for (int r = 0; r < 4; ++r) {
                const int t = lg * 4 + r;
                float g = a1[q][r];
                float h = g / (1.f + __expf(-g)) * a3[q][r] * ssw[t];
                u16 hh16, hl16; split1(h, hh16, hl16);
                const int col = j0 + q * 16 + lr;
                const int off = t * 512 + ((col * 2) ^ ((t & 7) << 4));
                *(u16*)((char*)hsh + off) = hh16;
                *(u16*)((char*)hsl + off) = hl16;
            }
        }
        __syncthreads();

        f32x4 ay[8] = {z4, z4, z4, z4, z4, z4, z4, z4};
        #pragma unroll 1
        for (int ks = 0; ks < 8; ++ks) {
            const int k0 = ks * 32 + lg * 8;
            const int hoff = lr * 512 + ((k0 * 2) ^ ((lr & 7) << 4));
            bf16x8 ah = *(const bf16x8*)((const char*)hsh + hoff);
            bf16x8 al = *(const bf16x8*)((const char*)hsl + hoff);
            #pragma unroll
            for (int q = 0; q < 8; ++q) {
                const size_t row = w2base + (size_t)(w * 128 + q * 16 + lr) * INTER + k0;
                bf16x8 bh = *(const bf16x8*)(w2th + row);
                bf16x8 bl = *(const bf16x8*)(w2tl + row);
                ay[q] = mfma16(ah, bh, ay[q]);
                ay[q] = mfma16(ah, bl, ay[q]);
                ay[q] = mfma16(al, bh, ay[q]);
            }
        }
        #pragma unroll
        for (int q = 0; q < 8; ++q) {
            #pragma unroll
            for (int r = 0; r < 4; ++r) {
                const int t = lg * 4 + r;
                if (t < cnt)
                    atomicAdd(&accum[(size_t)stok[t] * DIM + w * 128 + q * 16 + lr],
                              ay[q][r]);
            }
        }
    }
}

// ============== legacy VALU kernels (bf16 inputs, or tiny-workspace fallback) ==============

template<bool BF>
__device__ __forceinline__ void shared_body(const void* __restrict__ xg,
                                            const void* __restrict__ wsg,
                                            const void* __restrict__ wsu,
                                            const void* __restrict__ wsd,
                                            float* __restrict__ accum,
                                            float* xs /*8*DIM*/, float* vsf /*8*SINTER*/) {
    const int t0 = blockIdx.x * 8;
    const int tid = threadIdx.x;

    for (int idx = tid; idx < 8 * 64; idx += 256) {
        int r = idx >> 6, c = idx & 63;
        ld8<BF>(xg, (size_t)(t0 + r) * DIM + c * 8, &xs[r * DIM + c * 8]);
    }
    __syncthreads();

    for (int jc = 0; jc < 4; ++jc) {
        int j = jc * 256 + tid;
        float ag[8] = {0}, au[8] = {0};
        for (int k = 0; k < 64; ++k) {
            float fg[8], fu[8];
            ld8<BF>(wsg, (size_t)j * DIM + k * 8, fg);
            ld8<BF>(wsu, (size_t)j * DIM + k * 8, fu);
            #pragma unroll
            for (int r = 0; r < 8; ++r) {
                float4 xa = *(const float4*)&xs[r * DIM + k * 8];
                float4 xb = *(const float4*)&xs[r * DIM + k * 8 + 4];
                fma44(ag[r], fg, xa, xb);
                fma44(au[r], fu, xa, xb);
            }
        }
        #pragma unroll
        for (int r = 0; r < 8; ++r) {
            float g = ag[r];
            vsf[r * SINTER + j] = g / (1.f + __expf(-g)) * au[r];
        }
    }
    __syncthreads();

    const int d0 = tid, d1 = tid + 256;
    float aca[8] = {0}, acb[8] = {0};
    for (int k = 0; k < 128; ++k) {
        float fa[8], fb[8];
        ld8<BF>(wsd, (size_t)d0 * SINTER + k * 8, fa);
        ld8<BF>(wsd, (size_t)d1 * SINTER + k * 8, fb);
        #pragma unroll
        for (int r = 0; r < 8; ++r) {
            float4 v0 = *(const float4*)&vsf[r * SINTER + k * 8];
            float4 v1 = *(const float4*)&vsf[r * SINTER + k * 8 + 4];
            fma44(aca[r], fa, v0, v1);
            fma44(acb[r], fb, v0, v1);
        }
    }
    #pragma unroll
    for (int r = 0; r < 8; ++r) {
        accum[(size_t)(t0 + r) * DIM + d0] = aca[r];
        accum[(size_t)(t0 + r) * DIM + d1] = acb[r];
    }
}

__global__ __launch_bounds__(256) void k_shared(const void* xg, const void* wsg,
                                                const void* wsu, const void* wsd,
                                                const int* __restrict__ flag,
                                                float* accum, int bfonly) {
    if (bfonly && !*flag) return;
    __shared__ __align__(16) float xs[8 * DIM];
    __shared__ __align__(16) float vsf[8 * SINTER];
    if (*flag) shared_body<true >(xg, wsg, wsu, wsd, accum, xs, vsf);
    else       shared_body<false>(xg, wsg, wsu, wsd, accum, xs, vsf);
}

template<bool BF>
__device__ __forceinline__ void routed_body(const void* __restrict__ xg,
                                            const void* __restrict__ w1,
                                            const void* __restrict__ w2,
                                            const void* __restrict__ w3,
                                            const int* __restrict__ offsets,
                                            const int* __restrict__ counts,
                                            const int* __restrict__ tokl,
                                            const float* __restrict__ wgtl,
                                            float* __restrict__ accum,
                                            float* xs /*16*DIM*/, float* hsf /*16*INTER*/,
                                            int* stok, float* ssw) {
    const int e = blockIdx.x & 63;
    const int slice = blockIdx.x >> 6;
    const int tid = threadIdx.x;
    const int n = counts[e];
    const int base = offsets[e];
    const size_t wbase = (size_t)e * INTER * DIM;

    for (int tile = slice * 16; tile < n; tile += 64) {
        const int nt = min(16, n - tile);
        __syncthreads();
        if (tid < 16) {
            int ok = tid < nt;
            stok[tid] = ok ? tokl[base + tile + tid] : 0;
            ssw[tid]  = ok ? wgtl[base + tile + tid] : 0.f;
        }
        __syncthreads();
        for (int idx = tid; idx < 16 * 64; idx += 256) {
            int r = idx >> 6, c = idx & 63;
            float* xp = &xs[r * DIM + c * 8];
            if (r < nt) {
                ld8<BF>(xg, (size_t)stok[r] * DIM + c * 8, xp);
            } else {
                #pragma unroll
                for (int q = 0; q < 8; ++q) xp[q] = 0.f;
            }
        }
        __syncthreads();

        {
            float a1[16] = {0}, a3[16] = {0};
            for (int k = 0; k < 64; ++k) {
                float f1[8], f3[8];
                ld8<BF>(w1, wbase + (size_t)tid * DIM + k * 8, f1);
                ld8<BF>(w3, wbase + (size_t)tid * DIM + k * 8, f3);
                #pragma unroll
                for (int t = 0; t < 16; ++t) {
                    float4 xa = *(const float4*)&xs[t * DIM + k * 8];
                    float4 xb = *(const float4*)&xs[t * DIM + k * 8 + 4];
                    fma44(a1[t], f1, xa, xb);
                    fma44(a3[t], f3, xa, xb);
                }
            }
            #pragma unroll
            for (int t = 0; t < 16; ++t) {
                float g = a1[t];
                hsf[t * INTER + tid] = g / (1.f + __expf(-g)) * a3[t] * ssw[t];
            }
        }
        __syncthreads();

        {
            const int d0 = 2 * tid;
            float ay0[16] = {0}, ay1[16] = {0};
            for (int i = 0; i < INTER; i += 4) {
                float b0[4], b1[4];
                #pragma unroll
                for (int ii = 0; ii < 4; ++ii)
                    ld2<BF>(w2, wbase + (size_t)(i + ii) * DIM + d0, b0[ii], b1[ii]);
                #pragma unroll
                for (int t = 0; t < 16; ++t) {
                    float4 h4 = *(const float4*)&hsf[t * INTER + i];
                    ay0[t] = fmaf(h4.x, b0[0], ay0[t]); ay0[t] = fmaf(h4.y, b0[1], ay0[t]);
                    ay0[t] = fmaf(h4.z, b0[2], ay0[t]); ay0[t] = fmaf(h4.w, b0[3], ay0[t]);
                    ay1[t] = fmaf(h4.x, b1[0], ay1[t]); ay1[t] = fmaf(h4.y, b1[1], ay1[t]);
                    ay1[t] = fmaf(h4.z, b1[2], ay1[t]); ay1[t] = fmaf(h4.w, b1[3], ay1[t]);
                }
            }
            for (int t = 0; t < nt; ++t) {
                float* dst = &accum[(size_t)stok[t] * DIM + d0];
                atomicAdd(dst, ay0[t]);
                atomicAdd(dst + 1, ay1[t]);
            }
        }
    }
}

__global__ __launch_bounds__(256) void k_routed(const void* xg, const void* w1,
                                                const void* w2, const void* w3,
                                                const int* __restrict__ flag,
                                                const int* offsets, const int* counts,
                                                const int* tokl, const float* wgtl,
                                                float* accum, int bfonly) {
    if (bfonly && !*flag) return;
    __shared__ __align__(16) float xs[16 * DIM];
    __shared__ __align__(16) float hsf[16 * INTER];
    __shared__ int   stok[16];
    __shared__ float ssw[16];
    if (*flag) routed_body<true >(xg, w1, w2, w3, offsets, counts, tokl, wgtl, accum, xs, hsf, stok, ssw);
    else       routed_body<false>(xg, w1, w2, w3, offsets, counts, tokl, wgtl, accum, xs, hsf, stok, ssw);
}

// ---------------- kernel 6: fp32 accum -> output (dtype per flag) ----------------
__global__ void k_final(const float* __restrict__ accum, void* __restrict__ out,
                        const int* __restrict__ flag) {
    int i = blockIdx.x * 256 + threadIdx.x;
    float2 v = ((const float2*)accum)[i];
    if (*flag) {
        ((u32*)out)[i] = (u32)f2bf(v.x) | ((u32)f2bf(v.y) << 16);
    } else {
        ((float2*)out)[i] = v;
    }
}

extern "C" void kernel_launch(void* const* d_in, const int* in_sizes, int n_in,
                              void* d_out, int out_size, void* d_ws, size_t ws_size,
                              hipStream_t stream) {
    const void* x   = d_in[0];
    const void* wg  = d_in[1];
    const void* w1  = d_in[2];
    const void* w2  = d_in[3];
    const void* w3  = d_in[4];
    const void* wsg = d_in[5];
    const void* wsu = d_in[6];
    const void* wsd = d_in[7];

    char* ws = (char*)d_ws;
    float* accum  = (float*)ws;                              // [0, 2MiB)
    char* ctrl    = ws + ((size_t)2 << 20);
    int* counts   = (int*)ctrl;
    int* offsets  = counts + 64;
    int* cursors  = offsets + 64;
    int* topki    = cursors + 64;                            // 6144 ints
    float* topkw  = (float*)(topki + T_TOK * TOPK);          // 6144 floats
    int* tokl     = (int*)(topkw + T_TOK * TOPK);            // 6144 ints
    float* wgtl   = (float*)(tokl + T_TOK * TOPK);           // 6144 floats
    int* flag     = (int*)(wgtl + T_TOK * TOPK);
    u16* w2th = (u16*)(ws + ((size_t)3   << 20));            // 16 MiB [3,19)
    u16* w2tl = (u16*)(ws + ((size_t)19  << 20));            // 16 MiB [19,35)
    u16* vh   = (u16*)(ws + ((size_t)35  << 20));            //  2 MiB [35,37)
    u16* vl   = (u16*)(ws + ((size_t)37  << 20));            //  2 MiB [37,39)
    u16* w1h  = (u16*)(ws + ((size_t)40  << 20));            // 16 MiB [40,56)
    u16* w1l  = (u16*)(ws + ((size_t)56  << 20));            // 16 MiB [56,72)
    u16* w3h  = (u16*)(ws + ((size_t)72  << 20));            // 16 MiB [72,88)
    u16* w3l  = (u16*)(ws + ((size_t)88  << 20));            // 16 MiB [88,104)
    u16* wsgh = (u16*)(ws + ((size_t)104 << 20));            // 1 MiB each...
    u16* wsgl = (u16*)(ws + ((size_t)105 << 20));
    u16* wsuh = (u16*)(ws + ((size_t)106 << 20));
    u16* wsul = (u16*)(ws + ((size_t)107 << 20));
    u16* wsdh = (u16*)(ws + ((size_t)108 << 20));
    u16* wsdl = (u16*)(ws + ((size_t)109 << 20));
    u16* xh   = (u16*)(ws + ((size_t)110 << 20));
    u16* xl   = (u16*)(ws + ((size_t)111 << 20));
    const bool fast2 = ws_size >= ((size_t)112 << 20);
    const bool fast1 = !fast2 && ws_size >= ((size_t)39 << 20);

    k_probe  <<<1, 64, 0, stream>>>((const u32*)x, flag);
    k_init   <<<1, 64, 0, stream>>>(counts);
    k_router <<<T_TOK, 64, 0, stream>>>(x, wg, flag, counts, topki, topkw);
    k_prefix <<<1, 64, 0, stream>>>(counts, offsets, cursors);
    k_scatter<<<4, 256, 0, stream>>>(topki, topkw, cursors, tokl, wgtl);

    if (fast2) {
        k_bsplit <<<9216, 256, 0, stream>>>((const float*)w1, (const float*)w3,
                                            (const float*)wsg, (const float*)wsu,
                                            (const float*)wsd, (const float*)x,
                                            w1h, w1l, w3h, w3l, wsgh, wsgl, wsuh, wsul,
                                            wsdh, wsdl, xh, xl, flag);
        k_w2ts   <<<1024, 256, 0, stream>>>((const float*)w2, w2th, w2tl, flag);
        k_shA4   <<<256, 256, 0, stream>>>(xh, xl, wsgh, wsgl, wsuh, wsul, vh, vl, flag);
        k_shB4   <<<512, 256, 0, stream>>>(vh, vl, wsdh, wsdl, accum, flag);
        k_routed_mfma4<<<512, 256, 0, stream>>>(xh, xl, w1h, w1l, w3h, w3l,
                                                w2th, w2tl, flag,
                                                offsets, counts, tokl, wgtl, accum);
        // bf16-input fallback (no-ops when flag==0)
        k_shared <<<128, 256, 0, stream>>>(x, wsg, wsu, wsd, flag, accum, 1);
        k_routed <<<256, 256, 0, stream>>>(x, w1, w2, w3, flag, offsets, counts, tokl, wgtl, accum, 1);
    } else if (fast1) {
        k_w2ts   <<<1024, 256, 0, stream>>>((const float*)w2, w2th, w2tl, flag);
        k_shA3   <<<256, 256, 0, stream>>>((const float*)x, (const float*)wsg,
                                           (const float*)wsu, vh, vl, flag);
        k_shB3   <<<512, 256, 0, stream>>>(vh, vl, (const float*)wsd, accum, flag);
        k_routed_mfma3<<<512, 256, 0, stream>>>((const float*)x, (const float*)w1,
                                                (const float*)w3, w2th, w2tl, flag,
                                                offsets, counts, tokl, wgtl, accum);
        k_shared <<<128, 256, 0, stream>>>(x, wsg, wsu, wsd, flag, accum, 1);
        k_routed <<<256, 256, 0, stream>>>(x, w1, w2, w3, flag, offsets, counts, tokl, wgtl, accum, 1);
    } else {
        // tiny workspace: legacy VALU path for both dtypes
        k_shared <<<128, 256, 0, stream>>>(x, wsg, wsu, wsd, flag, accum, 0);
        k_routed <<<256, 256, 0, stream>>>(x, w1, w2, w3, flag, offsets, counts, tokl, wgtl, accum, 0);
    }
    k_final  <<<1024, 256, 0, stream>>>(accum, d_out, flag);
}